// Round 1
// baseline (253.594 us; speedup 1.0000x reference)
//
#include <hip/hip_runtime.h>
#include <hip/hip_bf16.h>
#include <cstdint>
#include <cstddef>

#define NNODES 50000
#define NEDGES 800000
// pass-1 partition by dst>>8: 256 chunks x 3125 edges, 256 digit rows (196 used)
#define NCH    256
#define CHUNK1 3125                        // 256*3125 = 800000 exact
#define NBUCK  196                         // ceil(50000/256)
#define GB1    782                         // ceil(50000/64) gemm blocks
#define DPB    64                          // degree-perm blocks
#define NPB    782                         // ceil(50000/64) nodes per perm block

typedef unsigned short u16;
typedef unsigned int u32;
typedef short bfrag8 __attribute__((ext_vector_type(8)));
typedef float f32x4 __attribute__((ext_vector_type(4)));

__device__ __forceinline__ u16 f2bf(float f) {
    union { float f; uint32_t i; } v; v.f = f;
    uint32_t r = (v.i + 0x7FFFu + ((v.i >> 16) & 1u)) >> 16;
    return (u16)r;
}
__device__ __forceinline__ float bflo(u32 p) { union { uint32_t i; float f; } v; v.i = p << 16; return v.f; }
__device__ __forceinline__ float bfhi(u32 p) { union { uint32_t i; float f; } v; v.i = p & 0xFFFF0000u; return v.f; }

// ===== launch 1: partition hist by dst>>8 + global-atomic degrees (blocks 0..255) | weight prep (256..383) =====
// degrees via device atomics into L2-resident 400KB arrays (zeroed by memsetAsync) — replaces the
// 64x100KB-LDS histogram blocks (1 block/CU serialization) + 12.8MB histg round-trip.
__global__ __launch_bounds__(256) void pre_kernel(const float* __restrict__ W1, const float* __restrict__ W2,
                                                  u16* __restrict__ P1, u16* __restrict__ P2,
                                                  const int* __restrict__ src, const int* __restrict__ dst,
                                                  int* __restrict__ deg_out, int* __restrict__ deg_in,
                                                  u32* __restrict__ gh1, int nE) {
    int b = blockIdx.x, t = threadIdx.x;
    if (b < NCH) {
        __shared__ u32 hh[NCH];
        hh[t] = 0;
        __syncthreads();
        int beg = b * CHUNK1, end = min(beg + CHUNK1, nE);
        for (int i = beg + t; i < end; i += 256) {
            int d = dst[i];
            atomicAdd(&hh[(u32)d >> 8], 1u);
            atomicAdd(&deg_in[d], 1);
            atomicAdd(&deg_out[src[i]], 1);
        }
        __syncthreads();
        gh1[t * NCH + b] = hh[t];          // gh1[digit][chunk]
    } else {
        int i = (b - NCH) * 256 + t;
        if (i < 256 * 128) {
            int k = i >> 7, n = i & 127;
            P1[((((k >> 3) << 7) + n) << 3) | (k & 7)] = f2bf(W1[i]);
        }
        if (i < 128 * 64) {
            int k = i >> 6, n = i & 63;
            P2[((((k >> 3) << 6) + n) << 3) | (k & 7)] = f2bf(W2[i]);
        }
    }
}

// ===== launch 2: per-digit-row inclusive scan of gh1 (blocks 0..255) | degree histogram for perm (256..319) =====
__global__ __launch_bounds__(256) void scan_hist(const u32* __restrict__ gh1, int* __restrict__ scan1,
                                                 int* __restrict__ part1, const int* __restrict__ deg_in,
                                                 int* __restrict__ gdh) {
    int t = threadIdx.x, b = blockIdx.x;
    if (b < NCH) {
        __shared__ int sd[256];
        int gi = b * NCH + t;              // digit row b, chunk t
        int v = (int)gh1[gi];
        sd[t] = v;
        __syncthreads();
        #pragma unroll
        for (int o = 1; o < 256; o <<= 1) {
            int add = (t >= o) ? sd[t - o] : 0;
            __syncthreads();
            sd[t] += add;
            __syncthreads();
        }
        scan1[gi] = sd[t];
        if (t == 255) part1[b] = sd[255];  // digit b total
    } else {
        // per-block degree histogram (64 bins) over a 782-node range
        int pb = b - NCH;
        __shared__ int cnt[64];
        if (t < 64) cnt[t] = 0;
        __syncthreads();
        int n0 = pb * NPB, n1 = min(n0 + NPB, NNODES);
        for (int n = n0 + t; n < n1; n += 256) {
            int d = deg_in[n]; d = d > 63 ? 63 : d;
            atomicAdd(&cnt[d], 1);
        }
        __syncthreads();
        if (t < 64) gdh[pb * 64 + t] = cnt[t];
    }
}

// ===== launch 3: partition scatter (blocks 0..255) | perm base scan (block 256) =====
__global__ __launch_bounds__(256) void scatter1(const int* __restrict__ dst, const int* __restrict__ src,
                                                const u32* __restrict__ gh1, const int* __restrict__ scan1,
                                                const int* __restrict__ part1, u32* __restrict__ sbuf,
                                                const int* __restrict__ gdh, int* __restrict__ gbase, int nE) {
    int t = threadIdx.x, c = blockIdx.x;
    if (c == NCH) {
        // bin-major exclusive offsets: gbase[pb][d] = sum_{d'<d} total[d'] + sum_{pb'<pb} gdh[pb'][d]
        __shared__ int colsum[64];
        if (t < 64) {
            int s = 0;
            for (int pb = 0; pb < DPB; pb++) s += gdh[pb * 64 + t];
            colsum[t] = s;
        }
        __syncthreads();
        if (t == 0) {
            int s = 0;
            for (int d = 0; d < 64; d++) { int c0 = colsum[d]; colsum[d] = s; s += c0; }
        }
        __syncthreads();
        if (t < 64) {
            int s = colsum[t];
            for (int pb = 0; pb < DPB; pb++) { gbase[pb * 64 + t] = s; s += gdh[pb * 64 + t]; }
        }
        return;
    }
    __shared__ int sd[256];
    __shared__ int offs[256];
    __shared__ u32 base[256];
    __shared__ u32 lh[256];
    int v = part1[t];
    sd[t] = v;
    __syncthreads();
    #pragma unroll
    for (int o = 1; o < 256; o <<= 1) {
        int add = (t >= o) ? sd[t - o] : 0;
        __syncthreads();
        sd[t] += add;
        __syncthreads();
    }
    offs[t] = sd[t] - v;                   // digit-level exclusive
    __syncthreads();
    base[t] = (u32)(scan1[t * NCH + c] + offs[t] - (int)gh1[t * NCH + c]);
    lh[t] = 0;
    __syncthreads();
    int beg = c * CHUNK1, end = min(beg + CHUNK1, nE);
    for (int i = beg + t; i < end; i += 256) {
        u32 el = ((u32)dst[i] << 16) | (u32)src[i];
        u32 d = el >> 24;                  // dst>>8
        u32 r = atomicAdd(&lh[d], 1);
        sbuf[base[d] + r] = el;
    }
}

// ============ dense gemm body (verified r8-r11) ============
template <int K, int N, bool AF32>
__device__ __forceinline__ void gemm_body(const void* __restrict__ A_, const u16* __restrict__ Wp,
                                          const int* __restrict__ deg, u16* __restrict__ out, int M, int bx) {
    const int lane = threadIdx.x & 63;
    const int wave = threadIdx.x >> 6;
    const int m = lane & 15;
    const int q = lane >> 4;
    const int row0 = bx * 64 + wave * 16;

    int rowa = row0 + m; if (rowa > M - 1) rowa = M - 1;

    constexpr int NT = N / 16;
    f32x4 acc[NT];
    #pragma unroll
    for (int t = 0; t < NT; t++) acc[t] = (f32x4){0.f, 0.f, 0.f, 0.f};

    #pragma unroll
    for (int kc = 0; kc < K; kc += 32) {
        bfrag8 af;
        if constexpr (AF32) {
            const float* ap = (const float*)A_ + (size_t)rowa * K + q * 8 + kc;
            const float4 x0 = *(const float4*)(ap);
            const float4 x1 = *(const float4*)(ap + 4);
            af[0] = (short)f2bf(x0.x); af[1] = (short)f2bf(x0.y);
            af[2] = (short)f2bf(x0.z); af[3] = (short)f2bf(x0.w);
            af[4] = (short)f2bf(x1.x); af[5] = (short)f2bf(x1.y);
            af[6] = (short)f2bf(x1.z); af[7] = (short)f2bf(x1.w);
        } else {
            const u16* ap = (const u16*)A_ + (size_t)rowa * K + q * 8 + kc;
            af = *(const bfrag8*)ap;
        }
        const u16* bbase = Wp + ((size_t)(((kc >> 3) + q) * N) + m) * 8;
        #pragma unroll
        for (int t = 0; t < NT; t++) {
            bfrag8 bf_ = *(const bfrag8*)(bbase + t * 128);
            acc[t] = __builtin_amdgcn_mfma_f32_16x16x32_bf16(af, bf_, acc[t], 0, 0, 0);
        }
    }
    #pragma unroll
    for (int r = 0; r < 4; r++) {
        int gr = row0 + q * 4 + r;
        if (gr < M) {
            int dO = deg[gr]; if (dO < 1) dO = 1;
            float s = rsqrtf((float)dO);
            #pragma unroll
            for (int t = 0; t < NT; t++)
                out[(size_t)gr * N + t * 16 + m] = f2bf(acc[t][r] * s);
        }
    }
}

template <int K, int N, bool AF32>
__global__ __launch_bounds__(256) void gemm_scaled(const void* __restrict__ A_, const u16* __restrict__ Wp,
                                                   const int* __restrict__ deg, u16* __restrict__ out, int M) {
    gemm_body<K, N, AF32>(A_, Wp, deg, out, M, blockIdx.x);
}

// ===== launch 4: per-bucket LDS counting sort + row_ptr (0..195) | layer-1 gemm (196..977) | perm scatter (978..1041) =====
__global__ __launch_bounds__(256) void sort_gemm(const u32* __restrict__ sbuf, const int* __restrict__ part1,
                                                 u32* __restrict__ sorted, int* __restrict__ rp,
                                                 const float* __restrict__ x, const u16* __restrict__ Wp1,
                                                 const int* __restrict__ deg_out, const int* __restrict__ deg_in,
                                                 const int* __restrict__ gbase, int* __restrict__ perm,
                                                 u16* __restrict__ h, int nE) {
    int b = blockIdx.x, t = threadIdx.x;
    if (b < NBUCK) {
        __shared__ int sd[256];
        __shared__ int cnt[256];
        __shared__ int cursor[256];
        // bucket bounds from digit totals
        int v = part1[t];
        sd[t] = v;
        __syncthreads();
        #pragma unroll
        for (int o = 1; o < 256; o <<= 1) {
            int add = (t >= o) ? sd[t - o] : 0;
            __syncthreads();
            sd[t] += add;
            __syncthreads();
        }
        __shared__ int bs_s, bl_s;
        if (t == b) { bs_s = sd[t] - v; bl_s = v; }
        __syncthreads();
        int bstart = bs_s, bend = bstart + bl_s;
        // sweep 1: count low bytes
        cnt[t] = 0;
        __syncthreads();
        for (int i = bstart + t; i < bend; i += 256)
            atomicAdd(&cnt[(sbuf[i] >> 16) & 255u], 1);
        __syncthreads();
        // scan counts -> row_ptr + cursors
        int cv = cnt[t];
        sd[t] = cv;
        __syncthreads();
        #pragma unroll
        for (int o = 1; o < 256; o <<= 1) {
            int add = (t >= o) ? sd[t - o] : 0;
            __syncthreads();
            sd[t] += add;
            __syncthreads();
        }
        int excl = sd[t] - cv;
        int node = b * 256 + t;
        if (node < NNODES) rp[node] = bstart + excl;
        if (b == NBUCK - 1 && t == 0) rp[NNODES] = nE;
        cursor[t] = excl;
        __syncthreads();
        // sweep 2: place (unstable within node — aggregation is commutative)
        for (int i = bstart + t; i < bend; i += 256) {
            u32 el = sbuf[i];
            int r = atomicAdd(&cursor[(el >> 16) & 255u], 1);
            sorted[bstart + r] = el;
        }
    } else if (b < NBUCK + GB1) {
        gemm_body<256, 128, true>(x, Wp1, deg_out, h, NNODES, b - NBUCK);
    } else {
        // perm scatter: counting-sort nodes by degree bin using precomputed bases
        int pb = b - NBUCK - GB1;
        __shared__ int cur[64];
        if (t < 64) cur[t] = gbase[pb * 64 + t];
        __syncthreads();
        int n0 = pb * NPB, n1 = min(n0 + NPB, NNODES);
        for (int n = n0 + t; n < n1; n += 256) {
            int d = deg_in[n]; d = d > 63 ? 63 : d;
            int p = atomicAdd(&cur[d], 1);
            perm[p] = n;
        }
    }
}

// ---- layer-1 gather: quarter-wave (16 lanes x 16B) per node, unroll-8, degree-balanced via perm ----
__global__ __launch_bounds__(256) void gather1(const uint4* __restrict__ h, const int* __restrict__ row_ptr,
                                               const u32* __restrict__ sorted, const float* __restrict__ b1,
                                               const int* __restrict__ perm,
                                               uint4* __restrict__ h1out, int nNodes) {
    int g = (blockIdx.x * 256 + threadIdx.x) >> 4;
    int l = threadIdx.x & 15;
    if (g >= nNodes) return;
    int node = perm[g];
    int beg = row_ptr[node], end = row_ptr[node + 1];
    float a[8] = {0.f, 0.f, 0.f, 0.f, 0.f, 0.f, 0.f, 0.f};
    for (int e = beg; e < end; e += 8) {
        uint4 p[8];
        #pragma unroll
        for (int j = 0; j < 8; j++) {
            int ee = e + j; ee = (ee < end - 1) ? ee : end - 1;
            p[j] = h[(size_t)(sorted[ee] & 0xFFFFu) * 16 + l];
        }
        #pragma unroll
        for (int j = 0; j < 8; j++)
            if (e + j < end) {
                a[0] += bflo(p[j].x); a[1] += bfhi(p[j].x);
                a[2] += bflo(p[j].y); a[3] += bfhi(p[j].y);
                a[4] += bflo(p[j].z); a[5] += bfhi(p[j].z);
                a[6] += bflo(p[j].w); a[7] += bfhi(p[j].w);
            }
    }
    int dI = end - beg; if (dI < 1) dI = 1;
    float r = rsqrtf((float)dI);
    const float4 bA = *(const float4*)(b1 + 8 * l);
    const float4 bB = *(const float4*)(b1 + 8 * l + 4);
    float v0 = fmaxf(a[0] * r + bA.x, 0.f), v1 = fmaxf(a[1] * r + bA.y, 0.f);
    float v2 = fmaxf(a[2] * r + bA.z, 0.f), v3 = fmaxf(a[3] * r + bA.w, 0.f);
    float v4 = fmaxf(a[4] * r + bB.x, 0.f), v5 = fmaxf(a[5] * r + bB.y, 0.f);
    float v6 = fmaxf(a[6] * r + bB.z, 0.f), v7 = fmaxf(a[7] * r + bB.w, 0.f);
    uint4 o;
    o.x = ((u32)f2bf(v1) << 16) | f2bf(v0);
    o.y = ((u32)f2bf(v3) << 16) | f2bf(v2);
    o.z = ((u32)f2bf(v5) << 16) | f2bf(v4);
    o.w = ((u32)f2bf(v7) << 16) | f2bf(v6);
    h1out[(size_t)node * 16 + l] = o;
}

// ---- layer-2 gather + projection: eighth-wave (8 lanes x 16B) per node, unroll-8, degree-balanced via perm ----
__global__ __launch_bounds__(256) void gather2(const uint4* __restrict__ h2, const int* __restrict__ row_ptr,
                                               const u32* __restrict__ sorted, const float* __restrict__ b2,
                                               const float* __restrict__ Wf, const float* __restrict__ bfv,
                                               const int* __restrict__ perm,
                                               float* __restrict__ logits, float* __restrict__ hidden, int nNodes) {
    int g = (blockIdx.x * 256 + threadIdx.x) >> 3;
    int l = threadIdx.x & 7;
    if (g >= nNodes) return;
    int node = perm[g];
    int beg = row_ptr[node], end = row_ptr[node + 1];
    float a[8] = {0.f, 0.f, 0.f, 0.f, 0.f, 0.f, 0.f, 0.f};
    for (int e = beg; e < end; e += 8) {
        uint4 p[8];
        #pragma unroll
        for (int j = 0; j < 8; j++) {
            int ee = e + j; ee = (ee < end - 1) ? ee : end - 1;
            p[j] = h2[(size_t)(sorted[ee] & 0xFFFFu) * 8 + l];
        }
        #pragma unroll
        for (int j = 0; j < 8; j++)
            if (e + j < end) {
                a[0] += bflo(p[j].x); a[1] += bfhi(p[j].x);
                a[2] += bflo(p[j].y); a[3] += bfhi(p[j].y);
                a[4] += bflo(p[j].z); a[5] += bfhi(p[j].z);
                a[6] += bflo(p[j].w); a[7] += bfhi(p[j].w);
            }
    }
    int dI = end - beg; if (dI < 1) dI = 1;
    float r = rsqrtf((float)dI);
    float v[8];
    #pragma unroll
    for (int f = 0; f < 8; f++) v[f] = a[f] * r + b2[8 * l + f];
    float4 oA = {v[0], v[1], v[2], v[3]};
    float4 oB = {v[4], v[5], v[6], v[7]};
    ((float4*)hidden)[(size_t)node * 16 + 2 * l + 0] = oA;
    ((float4*)hidden)[(size_t)node * 16 + 2 * l + 1] = oB;
    float l0 = 0.f, l1 = 0.f;
    #pragma unroll
    for (int f = 0; f < 8; f++) {
        l0 += v[f] * Wf[(8 * l + f) * 2 + 0];
        l1 += v[f] * Wf[(8 * l + f) * 2 + 1];
    }
    #pragma unroll
    for (int off = 4; off > 0; off >>= 1) {
        l0 += __shfl_down(l0, off, 8);
        l1 += __shfl_down(l1, off, 8);
    }
    if (l == 0) {
        logits[(size_t)node * 2 + 0] = l0 + bfv[0];
        logits[(size_t)node * 2 + 1] = l1 + bfv[1];
    }
}

extern "C" void kernel_launch(void* const* d_in, const int* in_sizes, int n_in,
                              void* d_out, int out_size, void* d_ws, size_t ws_size,
                              hipStream_t stream) {
    const float* x   = (const float*)d_in[0];
    const float* W1  = (const float*)d_in[1];
    const float* b1  = (const float*)d_in[2];
    const float* W2  = (const float*)d_in[3];
    const float* b2  = (const float*)d_in[4];
    const float* Wf  = (const float*)d_in[5];
    const float* bfv = (const float*)d_in[6];
    const int* src = (const int*)d_in[7];
    const int* dst = (const int*)d_in[8];

    float* out_logits = (float*)d_out;
    float* out_hidden = (float*)d_out + 2 * NNODES;

    char* ws = (char*)d_ws;
    size_t off = 0;
    auto alloc = [&](size_t bytes) { void* p = ws + off; off += (bytes + 255) & ~(size_t)255; return p; };
    u32*   gh1     = (u32*)alloc(NCH * NCH * 4);            // 256 KB
    int*   scan1   = (int*)alloc(NCH * NCH * 4);
    int*   part1   = (int*)alloc(256 * 4);
    u32*   sbuf    = (u32*)alloc((size_t)NEDGES * 4);
    u32*   sorted  = (u32*)alloc((size_t)NEDGES * 4);
    int*   deg     = (int*)alloc(2 * NNODES * 4);           // [0..N)=deg_out, [N..2N)=deg_in
    int*   row_ptr = (int*)alloc((NNODES + 1) * 4);
    int*   gdh     = (int*)alloc(DPB * 64 * 4);
    int*   gbase   = (int*)alloc(DPB * 64 * 4);
    int*   perm    = (int*)alloc(NNODES * 4);
    u16*   Wp1     = (u16*)alloc(256 * 128 * 2);
    u16*   Wp2     = (u16*)alloc(128 * 64 * 2);
    u16*   h       = (u16*)alloc((size_t)NNODES * 128 * 2);
    u16*   h1      = (u16*)alloc((size_t)NNODES * 128 * 2);
    u16*   h2      = (u16*)alloc((size_t)NNODES * 64 * 2);

    int* deg_out = deg;
    int* deg_in  = deg + NNODES;

    // 0: zero degree accumulators (graph-capturable async memset node)
    hipMemsetAsync(deg, 0, 2 * NNODES * sizeof(int), stream);
    // 1: partition hist (dst>>8) + global-atomic degrees + weight prep
    pre_kernel<<<NCH + 128, 256, 0, stream>>>(W1, W2, Wp1, Wp2, src, dst, deg_out, deg_in, gh1, NEDGES);
    // 2: per-digit scan + degree histogram for perm
    scan_hist<<<NCH + DPB, 256, 0, stream>>>(gh1, scan1, part1, deg_in, gdh);
    // 3: partition into 196 dst-range buckets + perm base scan
    scatter1<<<NCH + 1, 256, 0, stream>>>(dst, src, gh1, scan1, part1, sbuf, gdh, gbase, NEDGES);
    // 4: per-bucket counting sort + row_ptr || layer-1 gemm || perm scatter (independent, fused launch)
    sort_gemm<<<NBUCK + GB1 + DPB, 256, 0, stream>>>(sbuf, part1, sorted, row_ptr, x, Wp1,
                                                     deg_out, deg_in, gbase, perm, h, NEDGES);
    // 5: layer-1 gather (degree-balanced)
    gather1<<<(NNODES * 16) / 256, 256, 0, stream>>>((const uint4*)h, row_ptr, sorted, b1, perm,
                                                     (uint4*)h1, NNODES);
    // 6: layer-2 gemm
    gemm_scaled<128, 64, false><<<GB1, 256, 0, stream>>>(h1, Wp2, deg_out, h2, NNODES);
    // 7: layer-2 gather + projection (degree-balanced)
    gather2<<<(NNODES * 8 + 255) / 256, 256, 0, stream>>>((const uint4*)h2, row_ptr, sorted, b2, Wf, bfv,
                                                          perm, out_logits, out_hidden, NNODES);
}

// Round 2
// 222.137 us; speedup vs baseline: 1.1416x; 1.1416x over previous
//
#include <hip/hip_runtime.h>
#include <hip/hip_bf16.h>
#include <cstdint>
#include <cstddef>

#define NNODES 50000
#define NEDGES 800000
// pass-1 partition by dst>>8: 256 chunks x 3125 edges, 256 digit rows (196 used)
#define NCH    256
#define CHUNK1 3125                        // 256*3125 = 800000 exact
#define NBUCK  196                         // ceil(50000/256)
#define GB1    782                         // ceil(50000/64) gemm blocks
#define SHB    32                          // degree-hist blocks per array (src, dst)
#define SHE    25000                       // 32*25000 = 800000 exact
#define PBN    256                         // perm blocks
#define PBR    196                         // nodes per perm block (256*196 = 50176 >= 50000)

typedef unsigned short u16;
typedef unsigned int u32;
typedef short bfrag8 __attribute__((ext_vector_type(8)));
typedef float f32x4 __attribute__((ext_vector_type(4)));

__device__ __forceinline__ u16 f2bf(float f) {
    union { float f; uint32_t i; } v; v.f = f;
    uint32_t r = (v.i + 0x7FFFu + ((v.i >> 16) & 1u)) >> 16;
    return (u16)r;
}
__device__ __forceinline__ float bflo(u32 p) { union { uint32_t i; float f; } v; v.i = p << 16; return v.f; }
__device__ __forceinline__ float bfhi(u32 p) { union { uint32_t i; float f; } v; v.i = p & 0xFFFF0000u; return v.f; }

// ===== launch 1: u8-packed degree hists (blocks 0..63) | partition hist by dst>>8 (64..319) | weight prep =====
// 50KB LDS (u8 x 50000 packed in u32) -> 3 blocks/CU. Max degree ~45 << 255, byte counts safe.
// Replaces round-1's scattered global atomics (52MB of HBM atomic writeback, 66us).
__global__ __launch_bounds__(256) void pre_kernel(const float* __restrict__ W1, const float* __restrict__ W2,
                                                  u16* __restrict__ P1, u16* __restrict__ P2,
                                                  const int* __restrict__ src, const int* __restrict__ dst,
                                                  u32* __restrict__ histS, u32* __restrict__ histD,
                                                  u32* __restrict__ gh1, int nE) {
    __shared__ u32 hh[12500];              // 50 KB
    int b = blockIdx.x, t = threadIdx.x;
    if (b < 2 * SHB) {
        const int* col = (b < SHB) ? src : dst;
        int bb = (b < SHB) ? b : b - SHB;
        for (int j = t; j < 12500; j += 256) hh[j] = 0;
        __syncthreads();
        int beg = bb * SHE, end = min(beg + SHE, nE);
        for (int i = beg + t; i < end; i += 256) {
            u32 n = (u32)col[i];
            atomicAdd(&hh[n >> 2], 1u << ((n & 3) * 8));
        }
        __syncthreads();
        u32* out = ((b < SHB) ? histS : histD) + (size_t)bb * 12500;
        for (int j = t; j < 12500; j += 256) out[j] = hh[j];
    } else if (b < 2 * SHB + NCH) {
        int c = b - 2 * SHB;
        hh[t] = 0;
        __syncthreads();
        int beg = c * CHUNK1, end = min(beg + CHUNK1, nE);
        for (int i = beg + t; i < end; i += 256)
            atomicAdd(&hh[(u32)dst[i] >> 8], 1u);
        __syncthreads();
        gh1[t * NCH + c] = hh[t];          // gh1[digit][chunk]
    } else {
        int i = (b - 2 * SHB - NCH) * 256 + t;
        if (i < 256 * 128) {
            int k = i >> 7, n = i & 127;
            P1[((((k >> 3) << 7) + n) << 3) | (k & 7)] = f2bf(W1[i]);
        }
        if (i < 128 * 64) {
            int k = i >> 6, n = i & 63;
            P2[((((k >> 3) << 6) + n) << 3) | (k & 7)] = f2bf(W2[i]);
        }
    }
}

// ===== launch 2: per-digit scan of gh1 + deg reduce (u8 partials) + per-block degree histogram (grid=256) =====
__global__ __launch_bounds__(256) void red_scan1(const u32* __restrict__ histS, const u32* __restrict__ histD,
                                                 int* __restrict__ deg_out, int* __restrict__ deg_in,
                                                 const u32* __restrict__ gh1, int* __restrict__ scan1,
                                                 int* __restrict__ part1, int* __restrict__ gdh) {
    int t = threadIdx.x, b = blockIdx.x;
    __shared__ int sd[256];
    __shared__ int cnt64[64];
    if (t < 64) cnt64[t] = 0;
    // digit-row inclusive scan
    int gi = b * NCH + t;                  // digit row b, chunk t
    int v = (int)gh1[gi];
    sd[t] = v;
    __syncthreads();
    #pragma unroll
    for (int o = 1; o < 256; o <<= 1) {
        int add = (t >= o) ? sd[t - o] : 0;
        __syncthreads();
        sd[t] += add;
        __syncthreads();
    }
    scan1[gi] = sd[t];
    if (t == 255) part1[b] = sd[255];      // digit b total
    // degree reduce over 32 u8 partials per array + degree-bin histogram for perm
    int n = b * PBR + t;
    if (t < PBR && n < NNODES) {
        int w = n >> 2, sh = (n & 3) * 8;
        int so = 0, si = 0;
        #pragma unroll 8
        for (int r = 0; r < SHB; r++) {
            so += (int)((histS[(size_t)r * 12500 + w] >> sh) & 255u);
            si += (int)((histD[(size_t)r * 12500 + w] >> sh) & 255u);
        }
        deg_out[n] = so;
        deg_in[n] = si;
        atomicAdd(&cnt64[si > 63 ? 63 : si], 1);
    }
    __syncthreads();
    if (t < 64) gdh[b * 64 + t] = cnt64[t];
}

// ===== launch 3: partition scatter (blocks 0..255) | perm base scan (block 256) =====
__global__ __launch_bounds__(256) void scatter1(const int* __restrict__ dst, const int* __restrict__ src,
                                                const u32* __restrict__ gh1, const int* __restrict__ scan1,
                                                const int* __restrict__ part1, u32* __restrict__ sbuf,
                                                const int* __restrict__ gdh, int* __restrict__ gbase, int nE) {
    int t = threadIdx.x, c = blockIdx.x;
    if (c == NCH) {
        // bin-major exclusive offsets: gbase[pb][d] = sum_{d'<d} total[d'] + sum_{pb'<pb} gdh[pb'][d]
        __shared__ int colsum[64];
        if (t < 64) {
            int s = 0;
            for (int pb = 0; pb < PBN; pb++) s += gdh[pb * 64 + t];
            colsum[t] = s;
        }
        __syncthreads();
        if (t == 0) {
            int s = 0;
            for (int d = 0; d < 64; d++) { int c0 = colsum[d]; colsum[d] = s; s += c0; }
        }
        __syncthreads();
        if (t < 64) {
            int s = colsum[t];
            for (int pb = 0; pb < PBN; pb++) { gbase[pb * 64 + t] = s; s += gdh[pb * 64 + t]; }
        }
        return;
    }
    __shared__ int sd[256];
    __shared__ int offs[256];
    __shared__ u32 base[256];
    __shared__ u32 lh[256];
    int v = part1[t];
    sd[t] = v;
    __syncthreads();
    #pragma unroll
    for (int o = 1; o < 256; o <<= 1) {
        int add = (t >= o) ? sd[t - o] : 0;
        __syncthreads();
        sd[t] += add;
        __syncthreads();
    }
    offs[t] = sd[t] - v;                   // digit-level exclusive
    __syncthreads();
    base[t] = (u32)(scan1[t * NCH + c] + offs[t] - (int)gh1[t * NCH + c]);
    lh[t] = 0;
    __syncthreads();
    int beg = c * CHUNK1, end = min(beg + CHUNK1, nE);
    for (int i = beg + t; i < end; i += 256) {
        u32 el = ((u32)dst[i] << 16) | (u32)src[i];
        u32 d = el >> 24;                  // dst>>8
        u32 r = atomicAdd(&lh[d], 1);
        sbuf[base[d] + r] = el;
    }
}

// ============ dense gemm body (verified r8-r11) ============
template <int K, int N, bool AF32>
__device__ __forceinline__ void gemm_body(const void* __restrict__ A_, const u16* __restrict__ Wp,
                                          const int* __restrict__ deg, u16* __restrict__ out, int M, int bx) {
    const int lane = threadIdx.x & 63;
    const int wave = threadIdx.x >> 6;
    const int m = lane & 15;
    const int q = lane >> 4;
    const int row0 = bx * 64 + wave * 16;

    int rowa = row0 + m; if (rowa > M - 1) rowa = M - 1;

    constexpr int NT = N / 16;
    f32x4 acc[NT];
    #pragma unroll
    for (int t = 0; t < NT; t++) acc[t] = (f32x4){0.f, 0.f, 0.f, 0.f};

    #pragma unroll
    for (int kc = 0; kc < K; kc += 32) {
        bfrag8 af;
        if constexpr (AF32) {
            const float* ap = (const float*)A_ + (size_t)rowa * K + q * 8 + kc;
            const float4 x0 = *(const float4*)(ap);
            const float4 x1 = *(const float4*)(ap + 4);
            af[0] = (short)f2bf(x0.x); af[1] = (short)f2bf(x0.y);
            af[2] = (short)f2bf(x0.z); af[3] = (short)f2bf(x0.w);
            af[4] = (short)f2bf(x1.x); af[5] = (short)f2bf(x1.y);
            af[6] = (short)f2bf(x1.z); af[7] = (short)f2bf(x1.w);
        } else {
            const u16* ap = (const u16*)A_ + (size_t)rowa * K + q * 8 + kc;
            af = *(const bfrag8*)ap;
        }
        const u16* bbase = Wp + ((size_t)(((kc >> 3) + q) * N) + m) * 8;
        #pragma unroll
        for (int t = 0; t < NT; t++) {
            bfrag8 bf_ = *(const bfrag8*)(bbase + t * 128);
            acc[t] = __builtin_amdgcn_mfma_f32_16x16x32_bf16(af, bf_, acc[t], 0, 0, 0);
        }
    }
    #pragma unroll
    for (int r = 0; r < 4; r++) {
        int gr = row0 + q * 4 + r;
        if (gr < M) {
            int dO = deg[gr]; if (dO < 1) dO = 1;
            float s = rsqrtf((float)dO);
            #pragma unroll
            for (int t = 0; t < NT; t++)
                out[(size_t)gr * N + t * 16 + m] = f2bf(acc[t][r] * s);
        }
    }
}

template <int K, int N, bool AF32>
__global__ __launch_bounds__(256) void gemm_scaled(const void* __restrict__ A_, const u16* __restrict__ Wp,
                                                   const int* __restrict__ deg, u16* __restrict__ out, int M) {
    gemm_body<K, N, AF32>(A_, Wp, deg, out, M, blockIdx.x);
}

// ===== launch 4: per-bucket counting sort + row_ptr (0..195) | layer-1 gemm (196..977) | perm scatter (978..1233) =====
__global__ __launch_bounds__(256) void sort_gemm(const u32* __restrict__ sbuf, const int* __restrict__ part1,
                                                 u32* __restrict__ sorted, int* __restrict__ rp,
                                                 const float* __restrict__ x, const u16* __restrict__ Wp1,
                                                 const int* __restrict__ deg_out, const int* __restrict__ deg_in,
                                                 const int* __restrict__ gbase, int* __restrict__ perm,
                                                 u16* __restrict__ h, int nE) {
    int b = blockIdx.x, t = threadIdx.x;
    if (b < NBUCK) {
        __shared__ int sd[256];
        __shared__ int cnt[256];
        __shared__ int cursor[256];
        // bucket bounds from digit totals
        int v = part1[t];
        sd[t] = v;
        __syncthreads();
        #pragma unroll
        for (int o = 1; o < 256; o <<= 1) {
            int add = (t >= o) ? sd[t - o] : 0;
            __syncthreads();
            sd[t] += add;
            __syncthreads();
        }
        __shared__ int bs_s, bl_s;
        if (t == b) { bs_s = sd[t] - v; bl_s = v; }
        __syncthreads();
        int bstart = bs_s, bend = bstart + bl_s;
        // sweep 1: count low bytes
        cnt[t] = 0;
        __syncthreads();
        for (int i = bstart + t; i < bend; i += 256)
            atomicAdd(&cnt[(sbuf[i] >> 16) & 255u], 1);
        __syncthreads();
        // scan counts -> row_ptr + cursors
        int cv = cnt[t];
        sd[t] = cv;
        __syncthreads();
        #pragma unroll
        for (int o = 1; o < 256; o <<= 1) {
            int add = (t >= o) ? sd[t - o] : 0;
            __syncthreads();
            sd[t] += add;
            __syncthreads();
        }
        int excl = sd[t] - cv;
        int node = b * 256 + t;
        if (node < NNODES) rp[node] = bstart + excl;
        if (b == NBUCK - 1 && t == 0) rp[NNODES] = nE;
        cursor[t] = excl;
        __syncthreads();
        // sweep 2: place (unstable within node — aggregation is commutative)
        for (int i = bstart + t; i < bend; i += 256) {
            u32 el = sbuf[i];
            int r = atomicAdd(&cursor[(el >> 16) & 255u], 1);
            sorted[bstart + r] = el;
        }
    } else if (b < NBUCK + GB1) {
        gemm_body<256, 128, true>(x, Wp1, deg_out, h, NNODES, b - NBUCK);
    } else {
        // perm scatter: counting-sort nodes by degree bin using precomputed bases
        int pb = b - NBUCK - GB1;          // 0..255
        __shared__ int cur[64];
        if (t < 64) cur[t] = gbase[pb * 64 + t];
        __syncthreads();
        int n = pb * PBR + t;
        if (t < PBR && n < NNODES) {
            int d = deg_in[n]; d = d > 63 ? 63 : d;
            int p = atomicAdd(&cur[d], 1);
            perm[p] = n;
        }
    }
}

// ---- layer-1 gather: quarter-wave (16 lanes x 16B) per node, unroll-8, degree-balanced via perm ----
__global__ __launch_bounds__(256) void gather1(const uint4* __restrict__ h, const int* __restrict__ row_ptr,
                                               const u32* __restrict__ sorted, const float* __restrict__ b1,
                                               const int* __restrict__ perm,
                                               uint4* __restrict__ h1out, int nNodes) {
    int g = (blockIdx.x * 256 + threadIdx.x) >> 4;
    int l = threadIdx.x & 15;
    if (g >= nNodes) return;
    int node = perm[g];
    int beg = row_ptr[node], end = row_ptr[node + 1];
    float a[8] = {0.f, 0.f, 0.f, 0.f, 0.f, 0.f, 0.f, 0.f};
    for (int e = beg; e < end; e += 8) {
        uint4 p[8];
        #pragma unroll
        for (int j = 0; j < 8; j++) {
            int ee = e + j; ee = (ee < end - 1) ? ee : end - 1;
            p[j] = h[(size_t)(sorted[ee] & 0xFFFFu) * 16 + l];
        }
        #pragma unroll
        for (int j = 0; j < 8; j++)
            if (e + j < end) {
                a[0] += bflo(p[j].x); a[1] += bfhi(p[j].x);
                a[2] += bflo(p[j].y); a[3] += bfhi(p[j].y);
                a[4] += bflo(p[j].z); a[5] += bfhi(p[j].z);
                a[6] += bflo(p[j].w); a[7] += bfhi(p[j].w);
            }
    }
    int dI = end - beg; if (dI < 1) dI = 1;
    float r = rsqrtf((float)dI);
    const float4 bA = *(const float4*)(b1 + 8 * l);
    const float4 bB = *(const float4*)(b1 + 8 * l + 4);
    float v0 = fmaxf(a[0] * r + bA.x, 0.f), v1 = fmaxf(a[1] * r + bA.y, 0.f);
    float v2 = fmaxf(a[2] * r + bA.z, 0.f), v3 = fmaxf(a[3] * r + bA.w, 0.f);
    float v4 = fmaxf(a[4] * r + bB.x, 0.f), v5 = fmaxf(a[5] * r + bB.y, 0.f);
    float v6 = fmaxf(a[6] * r + bB.z, 0.f), v7 = fmaxf(a[7] * r + bB.w, 0.f);
    uint4 o;
    o.x = ((u32)f2bf(v1) << 16) | f2bf(v0);
    o.y = ((u32)f2bf(v3) << 16) | f2bf(v2);
    o.z = ((u32)f2bf(v5) << 16) | f2bf(v4);
    o.w = ((u32)f2bf(v7) << 16) | f2bf(v6);
    h1out[(size_t)node * 16 + l] = o;
}

// ---- layer-2 gather + projection: eighth-wave (8 lanes x 16B) per node, unroll-8, degree-balanced via perm ----
__global__ __launch_bounds__(256) void gather2(const uint4* __restrict__ h2, const int* __restrict__ row_ptr,
                                               const u32* __restrict__ sorted, const float* __restrict__ b2,
                                               const float* __restrict__ Wf, const float* __restrict__ bfv,
                                               const int* __restrict__ perm,
                                               float* __restrict__ logits, float* __restrict__ hidden, int nNodes) {
    int g = (blockIdx.x * 256 + threadIdx.x) >> 3;
    int l = threadIdx.x & 7;
    if (g >= nNodes) return;
    int node = perm[g];
    int beg = row_ptr[node], end = row_ptr[node + 1];
    float a[8] = {0.f, 0.f, 0.f, 0.f, 0.f, 0.f, 0.f, 0.f};
    for (int e = beg; e < end; e += 8) {
        uint4 p[8];
        #pragma unroll
        for (int j = 0; j < 8; j++) {
            int ee = e + j; ee = (ee < end - 1) ? ee : end - 1;
            p[j] = h2[(size_t)(sorted[ee] & 0xFFFFu) * 8 + l];
        }
        #pragma unroll
        for (int j = 0; j < 8; j++)
            if (e + j < end) {
                a[0] += bflo(p[j].x); a[1] += bfhi(p[j].x);
                a[2] += bflo(p[j].y); a[3] += bfhi(p[j].y);
                a[4] += bflo(p[j].z); a[5] += bfhi(p[j].z);
                a[6] += bflo(p[j].w); a[7] += bfhi(p[j].w);
            }
    }
    int dI = end - beg; if (dI < 1) dI = 1;
    float r = rsqrtf((float)dI);
    float v[8];
    #pragma unroll
    for (int f = 0; f < 8; f++) v[f] = a[f] * r + b2[8 * l + f];
    float4 oA = {v[0], v[1], v[2], v[3]};
    float4 oB = {v[4], v[5], v[6], v[7]};
    ((float4*)hidden)[(size_t)node * 16 + 2 * l + 0] = oA;
    ((float4*)hidden)[(size_t)node * 16 + 2 * l + 1] = oB;
    float l0 = 0.f, l1 = 0.f;
    #pragma unroll
    for (int f = 0; f < 8; f++) {
        l0 += v[f] * Wf[(8 * l + f) * 2 + 0];
        l1 += v[f] * Wf[(8 * l + f) * 2 + 1];
    }
    #pragma unroll
    for (int off = 4; off > 0; off >>= 1) {
        l0 += __shfl_down(l0, off, 8);
        l1 += __shfl_down(l1, off, 8);
    }
    if (l == 0) {
        logits[(size_t)node * 2 + 0] = l0 + bfv[0];
        logits[(size_t)node * 2 + 1] = l1 + bfv[1];
    }
}

extern "C" void kernel_launch(void* const* d_in, const int* in_sizes, int n_in,
                              void* d_out, int out_size, void* d_ws, size_t ws_size,
                              hipStream_t stream) {
    const float* x   = (const float*)d_in[0];
    const float* W1  = (const float*)d_in[1];
    const float* b1  = (const float*)d_in[2];
    const float* W2  = (const float*)d_in[3];
    const float* b2  = (const float*)d_in[4];
    const float* Wf  = (const float*)d_in[5];
    const float* bfv = (const float*)d_in[6];
    const int* src = (const int*)d_in[7];
    const int* dst = (const int*)d_in[8];

    float* out_logits = (float*)d_out;
    float* out_hidden = (float*)d_out + 2 * NNODES;

    char* ws = (char*)d_ws;
    size_t off = 0;
    auto alloc = [&](size_t bytes) { void* p = ws + off; off += (bytes + 255) & ~(size_t)255; return p; };
    u32*   gh1     = (u32*)alloc(NCH * NCH * 4);            // 256 KB
    int*   scan1   = (int*)alloc(NCH * NCH * 4);
    int*   part1   = (int*)alloc(256 * 4);
    u32*   sbuf    = (u32*)alloc((size_t)NEDGES * 4);
    u32*   sorted  = (u32*)alloc((size_t)NEDGES * 4);
    u32*   histS   = (u32*)alloc((size_t)SHB * 12500 * 4);  // 1.6 MB u8-packed partials
    u32*   histD   = (u32*)alloc((size_t)SHB * 12500 * 4);  // 1.6 MB
    int*   deg     = (int*)alloc(2 * NNODES * 4);           // [0..N)=deg_out, [N..2N)=deg_in
    int*   row_ptr = (int*)alloc((NNODES + 1) * 4);
    int*   gdh     = (int*)alloc(PBN * 64 * 4);
    int*   gbase   = (int*)alloc(PBN * 64 * 4);
    int*   perm    = (int*)alloc(NNODES * 4);
    u16*   Wp1     = (u16*)alloc(256 * 128 * 2);
    u16*   Wp2     = (u16*)alloc(128 * 64 * 2);
    u16*   h       = (u16*)alloc((size_t)NNODES * 128 * 2);
    u16*   h1      = (u16*)alloc((size_t)NNODES * 128 * 2);
    u16*   h2      = (u16*)alloc((size_t)NNODES * 64 * 2);

    int* deg_out = deg;
    int* deg_in  = deg + NNODES;

    // 1: u8 degree hists + partition hist (dst>>8) + weight prep
    pre_kernel<<<2 * SHB + NCH + 128, 256, 0, stream>>>(W1, W2, Wp1, Wp2, src, dst, histS, histD, gh1, NEDGES);
    // 2: per-digit scan + deg reduce + per-block degree histogram
    red_scan1<<<NCH, 256, 0, stream>>>(histS, histD, deg_out, deg_in, gh1, scan1, part1, gdh);
    // 3: partition into 196 dst-range buckets + perm base scan
    scatter1<<<NCH + 1, 256, 0, stream>>>(dst, src, gh1, scan1, part1, sbuf, gdh, gbase, NEDGES);
    // 4: per-bucket counting sort + row_ptr || layer-1 gemm || perm scatter (independent, fused launch)
    sort_gemm<<<NBUCK + GB1 + PBN, 256, 0, stream>>>(sbuf, part1, sorted, row_ptr, x, Wp1,
                                                     deg_out, deg_in, gbase, perm, h, NEDGES);
    // 5: layer-1 gather (degree-balanced)
    gather1<<<(NNODES * 16) / 256, 256, 0, stream>>>((const uint4*)h, row_ptr, sorted, b1, perm,
                                                     (uint4*)h1, NNODES);
    // 6: layer-2 gemm
    gemm_scaled<128, 64, false><<<GB1, 256, 0, stream>>>(h1, Wp2, deg_out, h2, NNODES);
    // 7: layer-2 gather + projection (degree-balanced)
    gather2<<<(NNODES * 8 + 255) / 256, 256, 0, stream>>>((const uint4*)h2, row_ptr, sorted, b2, Wf, bfv,
                                                          perm, out_logits, out_hidden, NNODES);
}

// Round 3
// 202.884 us; speedup vs baseline: 1.2499x; 1.0949x over previous
//
#include <hip/hip_runtime.h>
#include <hip/hip_bf16.h>
#include <cstdint>
#include <cstddef>

#define NNODES 50000
#define NEDGES 800000
// pass-1 partition by dst>>8: 256 chunks x 3125 edges, 256 digit rows (196 used)
#define NCH    256
#define CHUNK1 3125                        // 256*3125 = 800000 exact
#define NBUCK  196                         // ceil(50000/256)
#define GB1    782                         // ceil(50000/64) gemm blocks
#define SHB    64                          // degree-hist blocks per array (src, dst)
#define SHE    12500                       // 64*12500 = 800000 exact; base byte offset 50000 is 16B-aligned
#define SHEV   (SHE / 1024)                // 12 full uint4 rounds (12*1024 = 12288)
#define PBN    256                         // perm blocks
#define PBR    196                         // nodes per perm block (256*196 = 50176 >= 50000)

typedef unsigned short u16;
typedef unsigned int u32;
typedef short bfrag8 __attribute__((ext_vector_type(8)));
typedef float f32x4 __attribute__((ext_vector_type(4)));

__device__ __forceinline__ u16 f2bf(float f) {
    union { float f; uint32_t i; } v; v.f = f;
    uint32_t r = (v.i + 0x7FFFu + ((v.i >> 16) & 1u)) >> 16;
    return (u16)r;
}
__device__ __forceinline__ float bflo(u32 p) { union { uint32_t i; float f; } v; v.i = p << 16; return v.f; }
__device__ __forceinline__ float bfhi(u32 p) { union { uint32_t i; float f; } v; v.i = p & 0xFFFF0000u; return v.f; }

// ===== launch 1: u8-packed degree hists (blocks 0..127, uint4 edge loads) | partition hist (128..383) | weight prep =====
// Round-2 lesson: 64 blocks x scalar loads = 98 dependent 900-cyc rounds -> 46us latency-bound.
// Now: 128 blocks x 12500 edges, uint4 loads (4 edges/load, 12 rounds, unroll-4 ILP).
__global__ __launch_bounds__(256) void pre_kernel(const float* __restrict__ W1, const float* __restrict__ W2,
                                                  u16* __restrict__ P1, u16* __restrict__ P2,
                                                  const int* __restrict__ src, const int* __restrict__ dst,
                                                  u32* __restrict__ histS, u32* __restrict__ histD,
                                                  u32* __restrict__ gh1, int nE) {
    __shared__ u32 hh[12500];              // 50 KB
    int b = blockIdx.x, t = threadIdx.x;
    if (b < 2 * SHB) {
        const int* col = (b < SHB) ? src : dst;
        int bb = (b < SHB) ? b : b - SHB;
        for (int j = t; j < 12500; j += 256) hh[j] = 0;
        __syncthreads();
        int beg = bb * SHE;
        const uint4* col4 = (const uint4*)(col + beg);
        #pragma unroll 4
        for (int k = 0; k < SHEV; k++) {
            uint4 e = col4[k * 256 + t];
            atomicAdd(&hh[e.x >> 2], 1u << ((e.x & 3) * 8));
            atomicAdd(&hh[e.y >> 2], 1u << ((e.y & 3) * 8));
            atomicAdd(&hh[e.z >> 2], 1u << ((e.z & 3) * 8));
            atomicAdd(&hh[e.w >> 2], 1u << ((e.w & 3) * 8));
        }
        for (int i = beg + SHEV * 1024 + t; i < beg + SHE; i += 256) {
            u32 n = (u32)col[i];
            atomicAdd(&hh[n >> 2], 1u << ((n & 3) * 8));
        }
        __syncthreads();
        u32* out = ((b < SHB) ? histS : histD) + (size_t)bb * 12500;
        for (int j = t; j < 12500; j += 256) out[j] = hh[j];
    } else if (b < 2 * SHB + NCH) {
        int c = b - 2 * SHB;
        hh[t] = 0;
        __syncthreads();
        int beg = c * CHUNK1, end = min(beg + CHUNK1, nE);
        for (int i = beg + t; i < end; i += 256)
            atomicAdd(&hh[(u32)dst[i] >> 8], 1u);
        __syncthreads();
        gh1[t * NCH + c] = hh[t];          // gh1[digit][chunk]
    } else {
        int i = (b - 2 * SHB - NCH) * 256 + t;
        if (i < 256 * 128) {
            int k = i >> 7, n = i & 127;
            P1[((((k >> 3) << 7) + n) << 3) | (k & 7)] = f2bf(W1[i]);
        }
        if (i < 128 * 64) {
            int k = i >> 6, n = i & 63;
            P2[((((k >> 3) << 6) + n) << 3) | (k & 7)] = f2bf(W2[i]);
        }
    }
}

// ===== launch 2: per-digit scan of gh1 + deg reduce (u8 partials) + per-block degree histogram (grid=256) =====
__global__ __launch_bounds__(256) void red_scan1(const u32* __restrict__ histS, const u32* __restrict__ histD,
                                                 int* __restrict__ deg_out, int* __restrict__ deg_in,
                                                 const u32* __restrict__ gh1, int* __restrict__ scan1,
                                                 int* __restrict__ part1, int* __restrict__ gdh) {
    int t = threadIdx.x, b = blockIdx.x;
    __shared__ int sd[256];
    __shared__ int cnt64[64];
    if (t < 64) cnt64[t] = 0;
    // digit-row inclusive scan
    int gi = b * NCH + t;                  // digit row b, chunk t
    int v = (int)gh1[gi];
    sd[t] = v;
    __syncthreads();
    #pragma unroll
    for (int o = 1; o < 256; o <<= 1) {
        int add = (t >= o) ? sd[t - o] : 0;
        __syncthreads();
        sd[t] += add;
        __syncthreads();
    }
    scan1[gi] = sd[t];
    if (t == 255) part1[b] = sd[255];      // digit b total
    // degree reduce over 64 u8 partials per array + degree-bin histogram for perm
    int n = b * PBR + t;
    if (t < PBR && n < NNODES) {
        int w = n >> 2, sh = (n & 3) * 8;
        int so = 0, si = 0;
        #pragma unroll 8
        for (int r = 0; r < SHB; r++) {
            so += (int)((histS[(size_t)r * 12500 + w] >> sh) & 255u);
            si += (int)((histD[(size_t)r * 12500 + w] >> sh) & 255u);
        }
        deg_out[n] = so;
        deg_in[n] = si;
        atomicAdd(&cnt64[si > 63 ? 63 : si], 1);
    }
    __syncthreads();
    if (t < 64) gdh[b * 64 + t] = cnt64[t];
}

// ===== launch 3: partition scatter (blocks 0..255) | perm base scan (block 256) =====
__global__ __launch_bounds__(256) void scatter1(const int* __restrict__ dst, const int* __restrict__ src,
                                                const u32* __restrict__ gh1, const int* __restrict__ scan1,
                                                const int* __restrict__ part1, u32* __restrict__ sbuf,
                                                const int* __restrict__ gdh, int* __restrict__ gbase, int nE) {
    int t = threadIdx.x, c = blockIdx.x;
    if (c == NCH) {
        // bin-major exclusive offsets: gbase[pb][d] = sum_{d'<d} total[d'] + sum_{pb'<pb} gdh[pb'][d]
        __shared__ int colsum[64];
        if (t < 64) {
            int s = 0;
            for (int pb = 0; pb < PBN; pb++) s += gdh[pb * 64 + t];
            colsum[t] = s;
        }
        __syncthreads();
        if (t == 0) {
            int s = 0;
            for (int d = 0; d < 64; d++) { int c0 = colsum[d]; colsum[d] = s; s += c0; }
        }
        __syncthreads();
        if (t < 64) {
            int s = colsum[t];
            for (int pb = 0; pb < PBN; pb++) { gbase[pb * 64 + t] = s; s += gdh[pb * 64 + t]; }
        }
        return;
    }
    __shared__ int sd[256];
    __shared__ int offs[256];
    __shared__ u32 base[256];
    __shared__ u32 lh[256];
    int v = part1[t];
    sd[t] = v;
    __syncthreads();
    #pragma unroll
    for (int o = 1; o < 256; o <<= 1) {
        int add = (t >= o) ? sd[t - o] : 0;
        __syncthreads();
        sd[t] += add;
        __syncthreads();
    }
    offs[t] = sd[t] - v;                   // digit-level exclusive
    __syncthreads();
    base[t] = (u32)(scan1[t * NCH + c] + offs[t] - (int)gh1[t * NCH + c]);
    lh[t] = 0;
    __syncthreads();
    int beg = c * CHUNK1, end = min(beg + CHUNK1, nE);
    for (int i = beg + t; i < end; i += 256) {
        u32 el = ((u32)dst[i] << 16) | (u32)src[i];
        u32 d = el >> 24;                  // dst>>8
        u32 r = atomicAdd(&lh[d], 1);
        sbuf[base[d] + r] = el;
    }
}

// ============ dense gemm body (verified r8-r11) ============
template <int K, int N, bool AF32>
__device__ __forceinline__ void gemm_body(const void* __restrict__ A_, const u16* __restrict__ Wp,
                                          const int* __restrict__ deg, u16* __restrict__ out, int M, int bx) {
    const int lane = threadIdx.x & 63;
    const int wave = threadIdx.x >> 6;
    const int m = lane & 15;
    const int q = lane >> 4;
    const int row0 = bx * 64 + wave * 16;

    int rowa = row0 + m; if (rowa > M - 1) rowa = M - 1;

    constexpr int NT = N / 16;
    f32x4 acc[NT];
    #pragma unroll
    for (int t = 0; t < NT; t++) acc[t] = (f32x4){0.f, 0.f, 0.f, 0.f};

    #pragma unroll
    for (int kc = 0; kc < K; kc += 32) {
        bfrag8 af;
        if constexpr (AF32) {
            const float* ap = (const float*)A_ + (size_t)rowa * K + q * 8 + kc;
            const float4 x0 = *(const float4*)(ap);
            const float4 x1 = *(const float4*)(ap + 4);
            af[0] = (short)f2bf(x0.x); af[1] = (short)f2bf(x0.y);
            af[2] = (short)f2bf(x0.z); af[3] = (short)f2bf(x0.w);
            af[4] = (short)f2bf(x1.x); af[5] = (short)f2bf(x1.y);
            af[6] = (short)f2bf(x1.z); af[7] = (short)f2bf(x1.w);
        } else {
            const u16* ap = (const u16*)A_ + (size_t)rowa * K + q * 8 + kc;
            af = *(const bfrag8*)ap;
        }
        const u16* bbase = Wp + ((size_t)(((kc >> 3) + q) * N) + m) * 8;
        #pragma unroll
        for (int t = 0; t < NT; t++) {
            bfrag8 bf_ = *(const bfrag8*)(bbase + t * 128);
            acc[t] = __builtin_amdgcn_mfma_f32_16x16x32_bf16(af, bf_, acc[t], 0, 0, 0);
        }
    }
    #pragma unroll
    for (int r = 0; r < 4; r++) {
        int gr = row0 + q * 4 + r;
        if (gr < M) {
            int dO = deg[gr]; if (dO < 1) dO = 1;
            float s = rsqrtf((float)dO);
            #pragma unroll
            for (int t = 0; t < NT; t++)
                out[(size_t)gr * N + t * 16 + m] = f2bf(acc[t][r] * s);
        }
    }
}

template <int K, int N, bool AF32>
__global__ __launch_bounds__(256) void gemm_scaled(const void* __restrict__ A_, const u16* __restrict__ Wp,
                                                   const int* __restrict__ deg, u16* __restrict__ out, int M) {
    gemm_body<K, N, AF32>(A_, Wp, deg, out, M, blockIdx.x);
}

// ===== launch 4: per-bucket counting sort + row_ptr (0..195) | layer-1 gemm (196..977) | perm scatter (978..1233) =====
__global__ __launch_bounds__(256) void sort_gemm(const u32* __restrict__ sbuf, const int* __restrict__ part1,
                                                 u32* __restrict__ sorted, int* __restrict__ rp,
                                                 const float* __restrict__ x, const u16* __restrict__ Wp1,
                                                 const int* __restrict__ deg_out, const int* __restrict__ deg_in,
                                                 const int* __restrict__ gbase, int* __restrict__ perm,
                                                 u16* __restrict__ h, int nE) {
    int b = blockIdx.x, t = threadIdx.x;
    if (b < NBUCK) {
        __shared__ int sd[256];
        __shared__ int cnt[256];
        __shared__ int cursor[256];
        // bucket bounds from digit totals
        int v = part1[t];
        sd[t] = v;
        __syncthreads();
        #pragma unroll
        for (int o = 1; o < 256; o <<= 1) {
            int add = (t >= o) ? sd[t - o] : 0;
            __syncthreads();
            sd[t] += add;
            __syncthreads();
        }
        __shared__ int bs_s, bl_s;
        if (t == b) { bs_s = sd[t] - v; bl_s = v; }
        __syncthreads();
        int bstart = bs_s, bend = bstart + bl_s;
        // sweep 1: count low bytes
        cnt[t] = 0;
        __syncthreads();
        for (int i = bstart + t; i < bend; i += 256)
            atomicAdd(&cnt[(sbuf[i] >> 16) & 255u], 1);
        __syncthreads();
        // scan counts -> row_ptr + cursors
        int cv = cnt[t];
        sd[t] = cv;
        __syncthreads();
        #pragma unroll
        for (int o = 1; o < 256; o <<= 1) {
            int add = (t >= o) ? sd[t - o] : 0;
            __syncthreads();
            sd[t] += add;
            __syncthreads();
        }
        int excl = sd[t] - cv;
        int node = b * 256 + t;
        if (node < NNODES) rp[node] = bstart + excl;
        if (b == NBUCK - 1 && t == 0) rp[NNODES] = nE;
        cursor[t] = excl;
        __syncthreads();
        // sweep 2: place (unstable within node — aggregation is commutative)
        for (int i = bstart + t; i < bend; i += 256) {
            u32 el = sbuf[i];
            int r = atomicAdd(&cursor[(el >> 16) & 255u], 1);
            sorted[bstart + r] = el;
        }
    } else if (b < NBUCK + GB1) {
        gemm_body<256, 128, true>(x, Wp1, deg_out, h, NNODES, b - NBUCK);
    } else {
        // perm scatter: counting-sort nodes by degree bin using precomputed bases
        int pb = b - NBUCK - GB1;          // 0..255
        __shared__ int cur[64];
        if (t < 64) cur[t] = gbase[pb * 64 + t];
        __syncthreads();
        int n = pb * PBR + t;
        if (t < PBR && n < NNODES) {
            int d = deg_in[n]; d = d > 63 ? 63 : d;
            int p = atomicAdd(&cur[d], 1);
            perm[p] = n;
        }
    }
}

// ---- layer-1 gather: quarter-wave (16 lanes x 16B) per node, unroll-8, degree-balanced via perm ----
__global__ __launch_bounds__(256) void gather1(const uint4* __restrict__ h, const int* __restrict__ row_ptr,
                                               const u32* __restrict__ sorted, const float* __restrict__ b1,
                                               const int* __restrict__ perm,
                                               uint4* __restrict__ h1out, int nNodes) {
    int g = (blockIdx.x * 256 + threadIdx.x) >> 4;
    int l = threadIdx.x & 15;
    if (g >= nNodes) return;
    int node = perm[g];
    int beg = row_ptr[node], end = row_ptr[node + 1];
    float a[8] = {0.f, 0.f, 0.f, 0.f, 0.f, 0.f, 0.f, 0.f};
    for (int e = beg; e < end; e += 8) {
        uint4 p[8];
        #pragma unroll
        for (int j = 0; j < 8; j++) {
            int ee = e + j; ee = (ee < end - 1) ? ee : end - 1;
            p[j] = h[(size_t)(sorted[ee] & 0xFFFFu) * 16 + l];
        }
        #pragma unroll
        for (int j = 0; j < 8; j++)
            if (e + j < end) {
                a[0] += bflo(p[j].x); a[1] += bfhi(p[j].x);
                a[2] += bflo(p[j].y); a[3] += bfhi(p[j].y);
                a[4] += bflo(p[j].z); a[5] += bfhi(p[j].z);
                a[6] += bflo(p[j].w); a[7] += bfhi(p[j].w);
            }
    }
    int dI = end - beg; if (dI < 1) dI = 1;
    float r = rsqrtf((float)dI);
    const float4 bA = *(const float4*)(b1 + 8 * l);
    const float4 bB = *(const float4*)(b1 + 8 * l + 4);
    float v0 = fmaxf(a[0] * r + bA.x, 0.f), v1 = fmaxf(a[1] * r + bA.y, 0.f);
    float v2 = fmaxf(a[2] * r + bA.z, 0.f), v3 = fmaxf(a[3] * r + bA.w, 0.f);
    float v4 = fmaxf(a[4] * r + bB.x, 0.f), v5 = fmaxf(a[5] * r + bB.y, 0.f);
    float v6 = fmaxf(a[6] * r + bB.z, 0.f), v7 = fmaxf(a[7] * r + bB.w, 0.f);
    uint4 o;
    o.x = ((u32)f2bf(v1) << 16) | f2bf(v0);
    o.y = ((u32)f2bf(v3) << 16) | f2bf(v2);
    o.z = ((u32)f2bf(v5) << 16) | f2bf(v4);
    o.w = ((u32)f2bf(v7) << 16) | f2bf(v6);
    h1out[(size_t)node * 16 + l] = o;
}

// ---- layer-2 gather + projection: eighth-wave (8 lanes x 16B) per node, unroll-8, degree-balanced via perm ----
__global__ __launch_bounds__(256) void gather2(const uint4* __restrict__ h2, const int* __restrict__ row_ptr,
                                               const u32* __restrict__ sorted, const float* __restrict__ b2,
                                               const float* __restrict__ Wf, const float* __restrict__ bfv,
                                               const int* __restrict__ perm,
                                               float* __restrict__ logits, float* __restrict__ hidden, int nNodes) {
    int g = (blockIdx.x * 256 + threadIdx.x) >> 3;
    int l = threadIdx.x & 7;
    if (g >= nNodes) return;
    int node = perm[g];
    int beg = row_ptr[node], end = row_ptr[node + 1];
    float a[8] = {0.f, 0.f, 0.f, 0.f, 0.f, 0.f, 0.f, 0.f};
    for (int e = beg; e < end; e += 8) {
        uint4 p[8];
        #pragma unroll
        for (int j = 0; j < 8; j++) {
            int ee = e + j; ee = (ee < end - 1) ? ee : end - 1;
            p[j] = h2[(size_t)(sorted[ee] & 0xFFFFu) * 8 + l];
        }
        #pragma unroll
        for (int j = 0; j < 8; j++)
            if (e + j < end) {
                a[0] += bflo(p[j].x); a[1] += bfhi(p[j].x);
                a[2] += bflo(p[j].y); a[3] += bfhi(p[j].y);
                a[4] += bflo(p[j].z); a[5] += bfhi(p[j].z);
                a[6] += bflo(p[j].w); a[7] += bfhi(p[j].w);
            }
    }
    int dI = end - beg; if (dI < 1) dI = 1;
    float r = rsqrtf((float)dI);
    float v[8];
    #pragma unroll
    for (int f = 0; f < 8; f++) v[f] = a[f] * r + b2[8 * l + f];
    float4 oA = {v[0], v[1], v[2], v[3]};
    float4 oB = {v[4], v[5], v[6], v[7]};
    ((float4*)hidden)[(size_t)node * 16 + 2 * l + 0] = oA;
    ((float4*)hidden)[(size_t)node * 16 + 2 * l + 1] = oB;
    float l0 = 0.f, l1 = 0.f;
    #pragma unroll
    for (int f = 0; f < 8; f++) {
        l0 += v[f] * Wf[(8 * l + f) * 2 + 0];
        l1 += v[f] * Wf[(8 * l + f) * 2 + 1];
    }
    #pragma unroll
    for (int off = 4; off > 0; off >>= 1) {
        l0 += __shfl_down(l0, off, 8);
        l1 += __shfl_down(l1, off, 8);
    }
    if (l == 0) {
        logits[(size_t)node * 2 + 0] = l0 + bfv[0];
        logits[(size_t)node * 2 + 1] = l1 + bfv[1];
    }
}

extern "C" void kernel_launch(void* const* d_in, const int* in_sizes, int n_in,
                              void* d_out, int out_size, void* d_ws, size_t ws_size,
                              hipStream_t stream) {
    const float* x   = (const float*)d_in[0];
    const float* W1  = (const float*)d_in[1];
    const float* b1  = (const float*)d_in[2];
    const float* W2  = (const float*)d_in[3];
    const float* b2  = (const float*)d_in[4];
    const float* Wf  = (const float*)d_in[5];
    const float* bfv = (const float*)d_in[6];
    const int* src = (const int*)d_in[7];
    const int* dst = (const int*)d_in[8];

    float* out_logits = (float*)d_out;
    float* out_hidden = (float*)d_out + 2 * NNODES;

    char* ws = (char*)d_ws;
    size_t off = 0;
    auto alloc = [&](size_t bytes) { void* p = ws + off; off += (bytes + 255) & ~(size_t)255; return p; };
    u32*   gh1     = (u32*)alloc(NCH * NCH * 4);            // 256 KB
    int*   scan1   = (int*)alloc(NCH * NCH * 4);
    int*   part1   = (int*)alloc(256 * 4);
    u32*   sbuf    = (u32*)alloc((size_t)NEDGES * 4);
    u32*   sorted  = (u32*)alloc((size_t)NEDGES * 4);
    u32*   histS   = (u32*)alloc((size_t)SHB * 12500 * 4);  // 3.2 MB u8-packed partials
    u32*   histD   = (u32*)alloc((size_t)SHB * 12500 * 4);  // 3.2 MB
    int*   deg     = (int*)alloc(2 * NNODES * 4);           // [0..N)=deg_out, [N..2N)=deg_in
    int*   row_ptr = (int*)alloc((NNODES + 1) * 4);
    int*   gdh     = (int*)alloc(PBN * 64 * 4);
    int*   gbase   = (int*)alloc(PBN * 64 * 4);
    int*   perm    = (int*)alloc(NNODES * 4);
    u16*   Wp1     = (u16*)alloc(256 * 128 * 2);
    u16*   Wp2     = (u16*)alloc(128 * 64 * 2);
    u16*   h       = (u16*)alloc((size_t)NNODES * 128 * 2);
    u16*   h1      = (u16*)alloc((size_t)NNODES * 128 * 2);
    u16*   h2      = (u16*)alloc((size_t)NNODES * 64 * 2);

    int* deg_out = deg;
    int* deg_in  = deg + NNODES;

    // 1: u8 degree hists (uint4 edge loads) + partition hist (dst>>8) + weight prep
    pre_kernel<<<2 * SHB + NCH + 128, 256, 0, stream>>>(W1, W2, Wp1, Wp2, src, dst, histS, histD, gh1, NEDGES);
    // 2: per-digit scan + deg reduce + per-block degree histogram
    red_scan1<<<NCH, 256, 0, stream>>>(histS, histD, deg_out, deg_in, gh1, scan1, part1, gdh);
    // 3: partition into 196 dst-range buckets + perm base scan
    scatter1<<<NCH + 1, 256, 0, stream>>>(dst, src, gh1, scan1, part1, sbuf, gdh, gbase, NEDGES);
    // 4: per-bucket counting sort + row_ptr || layer-1 gemm || perm scatter (independent, fused launch)
    sort_gemm<<<NBUCK + GB1 + PBN, 256, 0, stream>>>(sbuf, part1, sorted, row_ptr, x, Wp1,
                                                     deg_out, deg_in, gbase, perm, h, NEDGES);
    // 5: layer-1 gather (degree-balanced)
    gather1<<<(NNODES * 16) / 256, 256, 0, stream>>>((const uint4*)h, row_ptr, sorted, b1, perm,
                                                     (uint4*)h1, NNODES);
    // 6: layer-2 gemm
    gemm_scaled<128, 64, false><<<GB1, 256, 0, stream>>>(h1, Wp2, deg_out, h2, NNODES);
    // 7: layer-2 gather + projection (degree-balanced)
    gather2<<<(NNODES * 8 + 255) / 256, 256, 0, stream>>>((const uint4*)h2, row_ptr, sorted, b2, Wf, bfv,
                                                          perm, out_logits, out_hidden, NNODES);
}

// Round 4
// 195.800 us; speedup vs baseline: 1.2952x; 1.0362x over previous
//
#include <hip/hip_runtime.h>
#include <hip/hip_bf16.h>
#include <cstdint>
#include <cstddef>

#define NNODES 50000
#define NEDGES 800000
// pass-1 partition by dst>>8: 256 chunks x 3136 edges (16B-aligned bases), 256 digit rows (196 used)
#define NCH    256
#define CHUNK1 3136                        // 255*3136 + 320 = 800000; every base 16B-aligned
#define NBUCK  196                         // ceil(50000/256)
#define GB1    782                         // ceil(50000/64) gemm blocks
#define SHB    64                          // degree-hist blocks per array (src, dst)
#define SHE    12500                       // 64*12500 = 800000 exact; base byte offset 50000 = 16*3125 aligned
#define SHEV   (SHE / 1024)                // 12 full uint4 rounds (12*1024 = 12288)
#define PBN    256                         // perm blocks
#define PBR    196                         // nodes per perm block (256*196 = 50176 >= 50000)

typedef unsigned short u16;
typedef unsigned int u32;
typedef short bfrag8 __attribute__((ext_vector_type(8)));
typedef float f32x4 __attribute__((ext_vector_type(4)));

__device__ __forceinline__ u16 f2bf(float f) {
    union { float f; uint32_t i; } v; v.f = f;
    uint32_t r = (v.i + 0x7FFFu + ((v.i >> 16) & 1u)) >> 16;
    return (u16)r;
}
__device__ __forceinline__ float bflo(u32 p) { union { uint32_t i; float f; } v; v.i = p << 16; return v.f; }
__device__ __forceinline__ float bfhi(u32 p) { union { uint32_t i; float f; } v; v.i = p & 0xFFFF0000u; return v.f; }

// ===== launch 1: u8-packed degree hists (0..127, uint4 loads) | partition hist (128..383, uint4) | weight prep =====
__global__ __launch_bounds__(256) void pre_kernel(const float* __restrict__ W1, const float* __restrict__ W2,
                                                  u16* __restrict__ P1, u16* __restrict__ P2,
                                                  const int* __restrict__ src, const int* __restrict__ dst,
                                                  u32* __restrict__ histS, u32* __restrict__ histD,
                                                  u32* __restrict__ gh1, int nE) {
    __shared__ u32 hh[12500];              // 50 KB
    int b = blockIdx.x, t = threadIdx.x;
    if (b < 2 * SHB) {
        const int* col = (b < SHB) ? src : dst;
        int bb = (b < SHB) ? b : b - SHB;
        for (int j = t; j < 12500; j += 256) hh[j] = 0;
        __syncthreads();
        int beg = bb * SHE;
        const uint4* col4 = (const uint4*)(col + beg);
        #pragma unroll 4
        for (int k = 0; k < SHEV; k++) {
            uint4 e = col4[k * 256 + t];
            atomicAdd(&hh[e.x >> 2], 1u << ((e.x & 3) * 8));
            atomicAdd(&hh[e.y >> 2], 1u << ((e.y & 3) * 8));
            atomicAdd(&hh[e.z >> 2], 1u << ((e.z & 3) * 8));
            atomicAdd(&hh[e.w >> 2], 1u << ((e.w & 3) * 8));
        }
        for (int i = beg + SHEV * 1024 + t; i < beg + SHE; i += 256) {
            u32 n = (u32)col[i];
            atomicAdd(&hh[n >> 2], 1u << ((n & 3) * 8));
        }
        __syncthreads();
        u32* out = ((b < SHB) ? histS : histD) + (size_t)bb * 12500;
        for (int j = t; j < 12500; j += 256) out[j] = hh[j];
    } else if (b < 2 * SHB + NCH) {
        int c = b - 2 * SHB;
        hh[t] = 0;
        __syncthreads();
        int beg = c * CHUNK1, end = min(beg + CHUNK1, nE);
        const uint4* d4 = (const uint4*)(dst + beg);
        int n4 = (end - beg) >> 2;         // chunk sizes divisible by 4
        for (int k = t; k < n4; k += 256) {
            uint4 e = d4[k];
            atomicAdd(&hh[e.x >> 8], 1u);
            atomicAdd(&hh[e.y >> 8], 1u);
            atomicAdd(&hh[e.z >> 8], 1u);
            atomicAdd(&hh[e.w >> 8], 1u);
        }
        __syncthreads();
        gh1[t * NCH + c] = hh[t];          // gh1[digit][chunk]
    } else {
        int i = (b - 2 * SHB - NCH) * 256 + t;
        if (i < 256 * 128) {
            int k = i >> 7, n = i & 127;
            P1[((((k >> 3) << 7) + n) << 3) | (k & 7)] = f2bf(W1[i]);
        }
        if (i < 128 * 64) {
            int k = i >> 6, n = i & 63;
            P2[((((k >> 3) << 6) + n) << 3) | (k & 7)] = f2bf(W2[i]);
        }
    }
}

// ===== launch 2: per-digit scan of gh1 + deg reduce (u8 partials) + per-block degree histogram (grid=256) =====
__global__ __launch_bounds__(256) void red_scan1(const u32* __restrict__ histS, const u32* __restrict__ histD,
                                                 int* __restrict__ deg_out, int* __restrict__ deg_in,
                                                 const u32* __restrict__ gh1, int* __restrict__ scan1,
                                                 int* __restrict__ part1, int* __restrict__ gdh) {
    int t = threadIdx.x, b = blockIdx.x;
    __shared__ int sd[256];
    __shared__ int cnt64[64];
    if (t < 64) cnt64[t] = 0;
    // digit-row inclusive scan
    int gi = b * NCH + t;                  // digit row b, chunk t
    int v = (int)gh1[gi];
    sd[t] = v;
    __syncthreads();
    #pragma unroll
    for (int o = 1; o < 256; o <<= 1) {
        int add = (t >= o) ? sd[t - o] : 0;
        __syncthreads();
        sd[t] += add;
        __syncthreads();
    }
    scan1[gi] = sd[t];
    if (t == 255) part1[b] = sd[255];      // digit b total
    // degree reduce over 64 u8 partials per array + degree-bin histogram for perm
    int n = b * PBR + t;
    if (t < PBR && n < NNODES) {
        int w = n >> 2, sh = (n & 3) * 8;
        int so = 0, si = 0;
        #pragma unroll 8
        for (int r = 0; r < SHB; r++) {
            so += (int)((histS[(size_t)r * 12500 + w] >> sh) & 255u);
            si += (int)((histD[(size_t)r * 12500 + w] >> sh) & 255u);
        }
        deg_out[n] = so;
        deg_in[n] = si;
        atomicAdd(&cnt64[si > 63 ? 63 : si], 1);
    }
    __syncthreads();
    if (t < 64) gdh[b * 64 + t] = cnt64[t];
}

// ===== launch 3: partition scatter (blocks 0..255, uint4 loads) | perm base scan (block 256) =====
__global__ __launch_bounds__(256) void scatter1(const int* __restrict__ dst, const int* __restrict__ src,
                                                const u32* __restrict__ gh1, const int* __restrict__ scan1,
                                                const int* __restrict__ part1, u32* __restrict__ sbuf,
                                                const int* __restrict__ gdh, int* __restrict__ gbase, int nE) {
    int t = threadIdx.x, c = blockIdx.x;
    if (c == NCH) {
        // bin-major exclusive offsets: gbase[pb][d] = sum_{d'<d} total[d'] + sum_{pb'<pb} gdh[pb'][d]
        __shared__ int colsum[64];
        if (t < 64) {
            int s = 0;
            for (int pb = 0; pb < PBN; pb++) s += gdh[pb * 64 + t];
            colsum[t] = s;
        }
        __syncthreads();
        if (t == 0) {
            int s = 0;
            for (int d = 0; d < 64; d++) { int c0 = colsum[d]; colsum[d] = s; s += c0; }
        }
        __syncthreads();
        if (t < 64) {
            int s = colsum[t];
            for (int pb = 0; pb < PBN; pb++) { gbase[pb * 64 + t] = s; s += gdh[pb * 64 + t]; }
        }
        return;
    }
    __shared__ int sd[256];
    __shared__ int offs[256];
    __shared__ u32 base[256];
    __shared__ u32 lh[256];
    int v = part1[t];
    sd[t] = v;
    __syncthreads();
    #pragma unroll
    for (int o = 1; o < 256; o <<= 1) {
        int add = (t >= o) ? sd[t - o] : 0;
        __syncthreads();
        sd[t] += add;
        __syncthreads();
    }
    offs[t] = sd[t] - v;                   // digit-level exclusive
    __syncthreads();
    base[t] = (u32)(scan1[t * NCH + c] + offs[t] - (int)gh1[t * NCH + c]);
    lh[t] = 0;
    __syncthreads();
    int beg = c * CHUNK1, end = min(beg + CHUNK1, nE);
    const uint4* s4 = (const uint4*)(src + beg);
    const uint4* d4 = (const uint4*)(dst + beg);
    int n4 = (end - beg) >> 2;
    for (int k = t; k < n4; k += 256) {
        uint4 es = s4[k], ed = d4[k];
        u32 el, dg, r;
        el = (ed.x << 16) | es.x; dg = el >> 24; r = atomicAdd(&lh[dg], 1); sbuf[base[dg] + r] = el;
        el = (ed.y << 16) | es.y; dg = el >> 24; r = atomicAdd(&lh[dg], 1); sbuf[base[dg] + r] = el;
        el = (ed.z << 16) | es.z; dg = el >> 24; r = atomicAdd(&lh[dg], 1); sbuf[base[dg] + r] = el;
        el = (ed.w << 16) | es.w; dg = el >> 24; r = atomicAdd(&lh[dg], 1); sbuf[base[dg] + r] = el;
    }
}

// ============ dense gemm body (verified r8-r11) ============
template <int K, int N, bool AF32>
__device__ __forceinline__ void gemm_body(const void* __restrict__ A_, const u16* __restrict__ Wp,
                                          const int* __restrict__ deg, u16* __restrict__ out, int M, int bx) {
    const int lane = threadIdx.x & 63;
    const int wave = threadIdx.x >> 6;
    const int m = lane & 15;
    const int q = lane >> 4;
    const int row0 = bx * 64 + wave * 16;

    int rowa = row0 + m; if (rowa > M - 1) rowa = M - 1;

    constexpr int NT = N / 16;
    f32x4 acc[NT];
    #pragma unroll
    for (int t = 0; t < NT; t++) acc[t] = (f32x4){0.f, 0.f, 0.f, 0.f};

    #pragma unroll
    for (int kc = 0; kc < K; kc += 32) {
        bfrag8 af;
        if constexpr (AF32) {
            const float* ap = (const float*)A_ + (size_t)rowa * K + q * 8 + kc;
            const float4 x0 = *(const float4*)(ap);
            const float4 x1 = *(const float4*)(ap + 4);
            af[0] = (short)f2bf(x0.x); af[1] = (short)f2bf(x0.y);
            af[2] = (short)f2bf(x0.z); af[3] = (short)f2bf(x0.w);
            af[4] = (short)f2bf(x1.x); af[5] = (short)f2bf(x1.y);
            af[6] = (short)f2bf(x1.z); af[7] = (short)f2bf(x1.w);
        } else {
            const u16* ap = (const u16*)A_ + (size_t)rowa * K + q * 8 + kc;
            af = *(const bfrag8*)ap;
        }
        const u16* bbase = Wp + ((size_t)(((kc >> 3) + q) * N) + m) * 8;
        #pragma unroll
        for (int t = 0; t < NT; t++) {
            bfrag8 bf_ = *(const bfrag8*)(bbase + t * 128);
            acc[t] = __builtin_amdgcn_mfma_f32_16x16x32_bf16(af, bf_, acc[t], 0, 0, 0);
        }
    }
    #pragma unroll
    for (int r = 0; r < 4; r++) {
        int gr = row0 + q * 4 + r;
        if (gr < M) {
            int dO = deg[gr]; if (dO < 1) dO = 1;
            float s = rsqrtf((float)dO);
            #pragma unroll
            for (int t = 0; t < NT; t++)
                out[(size_t)gr * N + t * 16 + m] = f2bf(acc[t][r] * s);
        }
    }
}

template <int K, int N, bool AF32>
__global__ __launch_bounds__(256) void gemm_scaled(const void* __restrict__ A_, const u16* __restrict__ Wp,
                                                   const int* __restrict__ deg, u16* __restrict__ out, int M) {
    gemm_body<K, N, AF32>(A_, Wp, deg, out, M, blockIdx.x);
}

// ===== launch 4: per-bucket counting sort + row_ptr (0..195) | layer-1 gemm (196..977) | perm scatter (978..1233) =====
__global__ __launch_bounds__(256) void sort_gemm(const u32* __restrict__ sbuf, const int* __restrict__ part1,
                                                 u32* __restrict__ sorted, int* __restrict__ rp,
                                                 const float* __restrict__ x, const u16* __restrict__ Wp1,
                                                 const int* __restrict__ deg_out, const int* __restrict__ deg_in,
                                                 const int* __restrict__ gbase, int* __restrict__ perm,
                                                 u16* __restrict__ h, int nE) {
    int b = blockIdx.x, t = threadIdx.x;
    if (b < NBUCK) {
        __shared__ int sd[256];
        __shared__ int cnt[256];
        __shared__ int cursor[256];
        // bucket bounds from digit totals
        int v = part1[t];
        sd[t] = v;
        __syncthreads();
        #pragma unroll
        for (int o = 1; o < 256; o <<= 1) {
            int add = (t >= o) ? sd[t - o] : 0;
            __syncthreads();
            sd[t] += add;
            __syncthreads();
        }
        __shared__ int bs_s, bl_s;
        if (t == b) { bs_s = sd[t] - v; bl_s = v; }
        __syncthreads();
        int bstart = bs_s, bend = bstart + bl_s;
        // sweep 1: count low bytes
        cnt[t] = 0;
        __syncthreads();
        for (int i = bstart + t; i < bend; i += 256)
            atomicAdd(&cnt[(sbuf[i] >> 16) & 255u], 1);
        __syncthreads();
        // scan counts -> row_ptr + cursors
        int cv = cnt[t];
        sd[t] = cv;
        __syncthreads();
        #pragma unroll
        for (int o = 1; o < 256; o <<= 1) {
            int add = (t >= o) ? sd[t - o] : 0;
            __syncthreads();
            sd[t] += add;
            __syncthreads();
        }
        int excl = sd[t] - cv;
        int node = b * 256 + t;
        if (node < NNODES) rp[node] = bstart + excl;
        if (b == NBUCK - 1 && t == 0) rp[NNODES] = nE;
        cursor[t] = excl;
        __syncthreads();
        // sweep 2: place (unstable within node — aggregation is commutative)
        for (int i = bstart + t; i < bend; i += 256) {
            u32 el = sbuf[i];
            int r = atomicAdd(&cursor[(el >> 16) & 255u], 1);
            sorted[bstart + r] = el;
        }
    } else if (b < NBUCK + GB1) {
        gemm_body<256, 128, true>(x, Wp1, deg_out, h, NNODES, b - NBUCK);
    } else {
        // perm scatter: counting-sort nodes by degree bin using precomputed bases
        int pb = b - NBUCK - GB1;          // 0..255
        __shared__ int cur[64];
        if (t < 64) cur[t] = gbase[pb * 64 + t];
        __syncthreads();
        int n = pb * PBR + t;
        if (t < PBR && n < NNODES) {
            int d = deg_in[n]; d = d > 63 ? 63 : d;
            int p = atomicAdd(&cur[d], 1);
            perm[p] = n;
        }
    }
}

// ---- layer-1 gather FUSED with layer-2 gemm: quarter-wave (16 lanes) per node; 16 nodes/block.
// After the aggregation each block holds 16 complete h1 rows -> stage to LDS (bf16, identical f2bf
// values that used to go to the h1 global buffer) -> 16x(16x16x32) MFMA tile per wave -> h2.
// Bit-identical to the former gather1 + gemm_scaled<128,64> pair; saves 25.6 MB round-trip + a launch.
__global__ __launch_bounds__(256) void gather1f(const uint4* __restrict__ h, const int* __restrict__ row_ptr,
                                                const u32* __restrict__ sorted, const float* __restrict__ b1,
                                                const int* __restrict__ perm, const int* __restrict__ deg_out,
                                                const u16* __restrict__ Wp2, u16* __restrict__ h2) {
    __shared__ __align__(16) u16 sh[16 * 136];   // 16 rows x (128 + 8 pad) bf16 = 4352 B; pad breaks bank aliasing
    int t = threadIdx.x;
    int qw = t >> 4;                       // block-local node index 0..15
    int l = t & 15;
    int g = blockIdx.x * 16 + qw;          // 3125 blocks x 16 = 50000 exact, no bounds check
    int node = perm[g];
    int beg = row_ptr[node], end = row_ptr[node + 1];
    float a[8] = {0.f, 0.f, 0.f, 0.f, 0.f, 0.f, 0.f, 0.f};
    for (int e = beg; e < end; e += 8) {
        uint4 p[8];
        #pragma unroll
        for (int j = 0; j < 8; j++) {
            int ee = e + j; ee = (ee < end - 1) ? ee : end - 1;
            p[j] = h[(size_t)(sorted[ee] & 0xFFFFu) * 16 + l];
        }
        #pragma unroll
        for (int j = 0; j < 8; j++)
            if (e + j < end) {
                a[0] += bflo(p[j].x); a[1] += bfhi(p[j].x);
                a[2] += bflo(p[j].y); a[3] += bfhi(p[j].y);
                a[4] += bflo(p[j].z); a[5] += bfhi(p[j].z);
                a[6] += bflo(p[j].w); a[7] += bfhi(p[j].w);
            }
    }
    int dI = end - beg; if (dI < 1) dI = 1;
    float r = rsqrtf((float)dI);
    const float4 bA = *(const float4*)(b1 + 8 * l);
    const float4 bB = *(const float4*)(b1 + 8 * l + 4);
    float v0 = fmaxf(a[0] * r + bA.x, 0.f), v1 = fmaxf(a[1] * r + bA.y, 0.f);
    float v2 = fmaxf(a[2] * r + bA.z, 0.f), v3 = fmaxf(a[3] * r + bA.w, 0.f);
    float v4 = fmaxf(a[4] * r + bB.x, 0.f), v5 = fmaxf(a[5] * r + bB.y, 0.f);
    float v6 = fmaxf(a[6] * r + bB.z, 0.f), v7 = fmaxf(a[7] * r + bB.w, 0.f);
    uint4 o;
    o.x = ((u32)f2bf(v1) << 16) | f2bf(v0);
    o.y = ((u32)f2bf(v3) << 16) | f2bf(v2);
    o.z = ((u32)f2bf(v5) << 16) | f2bf(v4);
    o.w = ((u32)f2bf(v7) << 16) | f2bf(v6);
    *(uint4*)&sh[qw * 136 + l * 8] = o;    // features [8l..8l+8) of row qw
    __syncthreads();
    // ---- layer-2 gemm tile: wave w computes cols [16w, 16w+16) of all 16 rows ----
    const int lane = t & 63;
    const int m = lane & 15;
    const int q = lane >> 4;
    const int w = t >> 6;
    f32x4 acc = (f32x4){0.f, 0.f, 0.f, 0.f};
    #pragma unroll
    for (int kc = 0; kc < 128; kc += 32) {
        bfrag8 af = *(const bfrag8*)&sh[m * 136 + q * 8 + kc];
        bfrag8 bf_ = *(const bfrag8*)(Wp2 + ((size_t)(((kc >> 3) + q) * 64) + w * 16 + m) * 8);
        acc = __builtin_amdgcn_mfma_f32_16x16x32_bf16(af, bf_, acc, 0, 0, 0);
    }
    #pragma unroll
    for (int rr = 0; rr < 4; rr++) {
        int li = q * 4 + rr;               // block-local row
        int nd = perm[blockIdx.x * 16 + li];
        int dO = deg_out[nd]; if (dO < 1) dO = 1;
        float s = rsqrtf((float)dO);
        h2[(size_t)nd * 64 + w * 16 + m] = f2bf(acc[rr] * s);
    }
}

// ---- layer-2 gather + projection: eighth-wave (8 lanes x 16B) per node, unroll-8, degree-balanced via perm ----
__global__ __launch_bounds__(256) void gather2(const uint4* __restrict__ h2, const int* __restrict__ row_ptr,
                                               const u32* __restrict__ sorted, const float* __restrict__ b2,
                                               const float* __restrict__ Wf, const float* __restrict__ bfv,
                                               const int* __restrict__ perm,
                                               float* __restrict__ logits, float* __restrict__ hidden, int nNodes) {
    int g = (blockIdx.x * 256 + threadIdx.x) >> 3;
    int l = threadIdx.x & 7;
    if (g >= nNodes) return;
    int node = perm[g];
    int beg = row_ptr[node], end = row_ptr[node + 1];
    float a[8] = {0.f, 0.f, 0.f, 0.f, 0.f, 0.f, 0.f, 0.f};
    for (int e = beg; e < end; e += 8) {
        uint4 p[8];
        #pragma unroll
        for (int j = 0; j < 8; j++) {
            int ee = e + j; ee = (ee < end - 1) ? ee : end - 1;
            p[j] = h2[(size_t)(sorted[ee] & 0xFFFFu) * 8 + l];
        }
        #pragma unroll
        for (int j = 0; j < 8; j++)
            if (e + j < end) {
                a[0] += bflo(p[j].x); a[1] += bfhi(p[j].x);
                a[2] += bflo(p[j].y); a[3] += bfhi(p[j].y);
                a[4] += bflo(p[j].z); a[5] += bfhi(p[j].z);
                a[6] += bflo(p[j].w); a[7] += bfhi(p[j].w);
            }
    }
    int dI = end - beg; if (dI < 1) dI = 1;
    float r = rsqrtf((float)dI);
    float v[8];
    #pragma unroll
    for (int f = 0; f < 8; f++) v[f] = a[f] * r + b2[8 * l + f];
    float4 oA = {v[0], v[1], v[2], v[3]};
    float4 oB = {v[4], v[5], v[6], v[7]};
    ((float4*)hidden)[(size_t)node * 16 + 2 * l + 0] = oA;
    ((float4*)hidden)[(size_t)node * 16 + 2 * l + 1] = oB;
    float l0 = 0.f, l1 = 0.f;
    #pragma unroll
    for (int f = 0; f < 8; f++) {
        l0 += v[f] * Wf[(8 * l + f) * 2 + 0];
        l1 += v[f] * Wf[(8 * l + f) * 2 + 1];
    }
    #pragma unroll
    for (int off = 4; off > 0; off >>= 1) {
        l0 += __shfl_down(l0, off, 8);
        l1 += __shfl_down(l1, off, 8);
    }
    if (l == 0) {
        logits[(size_t)node * 2 + 0] = l0 + bfv[0];
        logits[(size_t)node * 2 + 1] = l1 + bfv[1];
    }
}

extern "C" void kernel_launch(void* const* d_in, const int* in_sizes, int n_in,
                              void* d_out, int out_size, void* d_ws, size_t ws_size,
                              hipStream_t stream) {
    const float* x   = (const float*)d_in[0];
    const float* W1  = (const float*)d_in[1];
    const float* b1  = (const float*)d_in[2];
    const float* W2  = (const float*)d_in[3];
    const float* b2  = (const float*)d_in[4];
    const float* Wf  = (const float*)d_in[5];
    const float* bfv = (const float*)d_in[6];
    const int* src = (const int*)d_in[7];
    const int* dst = (const int*)d_in[8];

    float* out_logits = (float*)d_out;
    float* out_hidden = (float*)d_out + 2 * NNODES;

    char* ws = (char*)d_ws;
    size_t off = 0;
    auto alloc = [&](size_t bytes) { void* p = ws + off; off += (bytes + 255) & ~(size_t)255; return p; };
    u32*   gh1     = (u32*)alloc(NCH * NCH * 4);            // 256 KB
    int*   scan1   = (int*)alloc(NCH * NCH * 4);
    int*   part1   = (int*)alloc(256 * 4);
    u32*   sbuf    = (u32*)alloc((size_t)NEDGES * 4);
    u32*   sorted  = (u32*)alloc((size_t)NEDGES * 4);
    u32*   histS   = (u32*)alloc((size_t)SHB * 12500 * 4);  // 3.2 MB u8-packed partials
    u32*   histD   = (u32*)alloc((size_t)SHB * 12500 * 4);  // 3.2 MB
    int*   deg     = (int*)alloc(2 * NNODES * 4);           // [0..N)=deg_out, [N..2N)=deg_in
    int*   row_ptr = (int*)alloc((NNODES + 1) * 4);
    int*   gdh     = (int*)alloc(PBN * 64 * 4);
    int*   gbase   = (int*)alloc(PBN * 64 * 4);
    int*   perm    = (int*)alloc(NNODES * 4);
    u16*   Wp1     = (u16*)alloc(256 * 128 * 2);
    u16*   Wp2     = (u16*)alloc(128 * 64 * 2);
    u16*   h       = (u16*)alloc((size_t)NNODES * 128 * 2);
    u16*   h2      = (u16*)alloc((size_t)NNODES * 64 * 2);

    int* deg_out = deg;
    int* deg_in  = deg + NNODES;

    // 1: u8 degree hists + partition hist (dst>>8) + weight prep (all uint4 edge loads)
    pre_kernel<<<2 * SHB + NCH + 128, 256, 0, stream>>>(W1, W2, Wp1, Wp2, src, dst, histS, histD, gh1, NEDGES);
    // 2: per-digit scan + deg reduce + per-block degree histogram
    red_scan1<<<NCH, 256, 0, stream>>>(histS, histD, deg_out, deg_in, gh1, scan1, part1, gdh);
    // 3: partition into 196 dst-range buckets + perm base scan
    scatter1<<<NCH + 1, 256, 0, stream>>>(dst, src, gh1, scan1, part1, sbuf, gdh, gbase, NEDGES);
    // 4: per-bucket counting sort + row_ptr || layer-1 gemm || perm scatter (independent, fused launch)
    sort_gemm<<<NBUCK + GB1 + PBN, 256, 0, stream>>>(sbuf, part1, sorted, row_ptr, x, Wp1,
                                                     deg_out, deg_in, gbase, perm, h, NEDGES);
    // 5: layer-1 gather fused with layer-2 gemm (degree-balanced; h1 round-trip eliminated)
    gather1f<<<NNODES / 16, 256, 0, stream>>>((const uint4*)h, row_ptr, sorted, b1, perm, deg_out, Wp2, h2);
    // 6: layer-2 gather + projection (degree-balanced)
    gather2<<<(NNODES * 8 + 255) / 256, 256, 0, stream>>>((const uint4*)h2, row_ptr, sorted, b2, Wf, bfv,
                                                          perm, out_logits, out_hidden, NNODES);
}

// Round 5
// 193.829 us; speedup vs baseline: 1.3083x; 1.0102x over previous
//
#include <hip/hip_runtime.h>
#include <hip/hip_bf16.h>
#include <cstdint>
#include <cstddef>

#define NNODES 50000
#define NEDGES 800000
// pass-1 partition by dst>>8: 256 chunks x 3136 edges (16B-aligned bases), 256 digit rows (196 used)
#define NCH    256
#define CHUNK1 3136                        // 255*3136 + 320 = 800000; every base 16B-aligned
#define NBUCK  196                         // ceil(50000/256)
#define GB1    782                         // ceil(50000/64) gemm blocks
#define SHB    64                          // degree-hist blocks per array (src, dst)
#define SHE    12500                       // 64*12500 = 800000 exact; base byte offset 50000 = 16*3125 aligned
#define SHEV   (SHE / 1024)                // 12 full uint4 rounds (12*1024 = 12288)
#define PBN    256                         // perm blocks
#define PBR    196                         // nodes per perm block (256*196 = 50176 >= 50000)

typedef unsigned short u16;
typedef unsigned int u32;
typedef short bfrag8 __attribute__((ext_vector_type(8)));
typedef float f32x4 __attribute__((ext_vector_type(4)));

__device__ __forceinline__ u16 f2bf(float f) {
    union { float f; uint32_t i; } v; v.f = f;
    uint32_t r = (v.i + 0x7FFFu + ((v.i >> 16) & 1u)) >> 16;
    return (u16)r;
}
__device__ __forceinline__ float bflo(u32 p) { union { uint32_t i; float f; } v; v.i = p << 16; return v.f; }
__device__ __forceinline__ float bfhi(u32 p) { union { uint32_t i; float f; } v; v.i = p & 0xFFFF0000u; return v.f; }

// ===== launch 1: u8-packed degree hists (0..127, uint4 loads) | partition hist (128..383, uint4) | weight prep =====
// gh1 now u16 [chunk][digit]: coalesced write here, coalesced streaming read in scat_deg.
__global__ __launch_bounds__(256) void pre_kernel(const float* __restrict__ W1, const float* __restrict__ W2,
                                                  u16* __restrict__ P1, u16* __restrict__ P2,
                                                  const int* __restrict__ src, const int* __restrict__ dst,
                                                  u32* __restrict__ histS, u32* __restrict__ histD,
                                                  u16* __restrict__ gh1, int nE) {
    __shared__ u32 hh[12500];              // 50 KB
    int b = blockIdx.x, t = threadIdx.x;
    if (b < 2 * SHB) {
        const int* col = (b < SHB) ? src : dst;
        int bb = (b < SHB) ? b : b - SHB;
        for (int j = t; j < 12500; j += 256) hh[j] = 0;
        __syncthreads();
        int beg = bb * SHE;
        const uint4* col4 = (const uint4*)(col + beg);
        #pragma unroll 4
        for (int k = 0; k < SHEV; k++) {
            uint4 e = col4[k * 256 + t];
            atomicAdd(&hh[e.x >> 2], 1u << ((e.x & 3) * 8));
            atomicAdd(&hh[e.y >> 2], 1u << ((e.y & 3) * 8));
            atomicAdd(&hh[e.z >> 2], 1u << ((e.z & 3) * 8));
            atomicAdd(&hh[e.w >> 2], 1u << ((e.w & 3) * 8));
        }
        for (int i = beg + SHEV * 1024 + t; i < beg + SHE; i += 256) {
            u32 n = (u32)col[i];
            atomicAdd(&hh[n >> 2], 1u << ((n & 3) * 8));
        }
        __syncthreads();
        u32* out = ((b < SHB) ? histS : histD) + (size_t)bb * 12500;
        for (int j = t; j < 12500; j += 256) out[j] = hh[j];
    } else if (b < 2 * SHB + NCH) {
        int c = b - 2 * SHB;
        hh[t] = 0;
        __syncthreads();
        int beg = c * CHUNK1, end = min(beg + CHUNK1, nE);
        const uint4* d4 = (const uint4*)(dst + beg);
        int n4 = (end - beg) >> 2;         // chunk sizes divisible by 4
        for (int k = t; k < n4; k += 256) {
            uint4 e = d4[k];
            atomicAdd(&hh[e.x >> 8], 1u);
            atomicAdd(&hh[e.y >> 8], 1u);
            atomicAdd(&hh[e.z >> 8], 1u);
            atomicAdd(&hh[e.w >> 8], 1u);
        }
        __syncthreads();
        gh1[c * NCH + t] = (u16)hh[t];     // [chunk][digit], coalesced
    } else {
        int i = (b - 2 * SHB - NCH) * 256 + t;
        if (i < 256 * 128) {
            int k = i >> 7, n = i & 127;
            P1[((((k >> 3) << 7) + n) << 3) | (k & 7)] = f2bf(W1[i]);
        }
        if (i < 128 * 64) {
            int k = i >> 6, n = i & 63;
            P2[((((k >> 3) << 6) + n) << 3) | (k & 7)] = f2bf(W2[i]);
        }
    }
}

// ===== launch 2: partition scatter + deg reduce + gdh (grid = 256) — merges old red_scan1 into scatter1 =====
// Each block streams gh1[cc][t] over all chunks cc: digit totals (tot) + own-chunk prefix (par) inline,
// replacing the scan1 buffer and one launch. base = digit_exclusive(tot) + par, identical arithmetic.
__global__ __launch_bounds__(256) void scat_deg(const int* __restrict__ src, const int* __restrict__ dst,
                                                const u16* __restrict__ gh1,
                                                const u32* __restrict__ histS, const u32* __restrict__ histD,
                                                int* __restrict__ deg_out, int* __restrict__ deg_in,
                                                int* __restrict__ gdh, int* __restrict__ part1,
                                                u32* __restrict__ sbuf, int nE) {
    int t = threadIdx.x, c = blockIdx.x;
    __shared__ int sd[256];
    __shared__ u32 base[256];
    __shared__ u32 lh[256];
    __shared__ int cnt64[64];
    if (t < 64) cnt64[t] = 0;
    int tot = 0, par = 0;
    #pragma unroll 8
    for (int cc = 0; cc < NCH; cc++) {
        int v = (int)gh1[cc * NCH + t];
        tot += v;
        par += (cc < c) ? v : 0;
    }
    if (c == 0) part1[t] = tot;            // digit totals for the sort blocks
    sd[t] = tot;
    __syncthreads();
    #pragma unroll
    for (int o = 1; o < 256; o <<= 1) {
        int add = (t >= o) ? sd[t - o] : 0;
        __syncthreads();
        sd[t] += add;
        __syncthreads();
    }
    base[t] = (u32)((sd[t] - tot) + par);  // digit-exclusive + chunk-prefix
    lh[t] = 0;
    __syncthreads();
    // scatter this chunk's edges into dst-range buckets
    int beg = c * CHUNK1, end = min(beg + CHUNK1, nE);
    const uint4* s4 = (const uint4*)(src + beg);
    const uint4* d4 = (const uint4*)(dst + beg);
    int n4 = (end - beg) >> 2;
    for (int k = t; k < n4; k += 256) {
        uint4 es = s4[k], ed = d4[k];
        u32 el, dg, r;
        el = (ed.x << 16) | es.x; dg = el >> 24; r = atomicAdd(&lh[dg], 1); sbuf[base[dg] + r] = el;
        el = (ed.y << 16) | es.y; dg = el >> 24; r = atomicAdd(&lh[dg], 1); sbuf[base[dg] + r] = el;
        el = (ed.z << 16) | es.z; dg = el >> 24; r = atomicAdd(&lh[dg], 1); sbuf[base[dg] + r] = el;
        el = (ed.w << 16) | es.w; dg = el >> 24; r = atomicAdd(&lh[dg], 1); sbuf[base[dg] + r] = el;
    }
    // deg reduce over 64 u8 partials per array + degree-bin histogram for the perm
    int n = c * PBR + t;
    if (t < PBR && n < NNODES) {
        int w = n >> 2, sh = (n & 3) * 8;
        int so = 0, si = 0;
        #pragma unroll 8
        for (int r = 0; r < SHB; r++) {
            so += (int)((histS[(size_t)r * 12500 + w] >> sh) & 255u);
            si += (int)((histD[(size_t)r * 12500 + w] >> sh) & 255u);
        }
        deg_out[n] = so;
        deg_in[n] = si;
        atomicAdd(&cnt64[si > 63 ? 63 : si], 1);
    }
    __syncthreads();
    if (t < 64) gdh[c * 64 + t] = cnt64[t];
}

// ============ dense gemm body (verified r8-r11) ============
template <int K, int N, bool AF32>
__device__ __forceinline__ void gemm_body(const void* __restrict__ A_, const u16* __restrict__ Wp,
                                          const int* __restrict__ deg, u16* __restrict__ out, int M, int bx) {
    const int lane = threadIdx.x & 63;
    const int wave = threadIdx.x >> 6;
    const int m = lane & 15;
    const int q = lane >> 4;
    const int row0 = bx * 64 + wave * 16;

    int rowa = row0 + m; if (rowa > M - 1) rowa = M - 1;

    constexpr int NT = N / 16;
    f32x4 acc[NT];
    #pragma unroll
    for (int t = 0; t < NT; t++) acc[t] = (f32x4){0.f, 0.f, 0.f, 0.f};

    #pragma unroll
    for (int kc = 0; kc < K; kc += 32) {
        bfrag8 af;
        if constexpr (AF32) {
            const float* ap = (const float*)A_ + (size_t)rowa * K + q * 8 + kc;
            const float4 x0 = *(const float4*)(ap);
            const float4 x1 = *(const float4*)(ap + 4);
            af[0] = (short)f2bf(x0.x); af[1] = (short)f2bf(x0.y);
            af[2] = (short)f2bf(x0.z); af[3] = (short)f2bf(x0.w);
            af[4] = (short)f2bf(x1.x); af[5] = (short)f2bf(x1.y);
            af[6] = (short)f2bf(x1.z); af[7] = (short)f2bf(x1.w);
        } else {
            const u16* ap = (const u16*)A_ + (size_t)rowa * K + q * 8 + kc;
            af = *(const bfrag8*)ap;
        }
        const u16* bbase = Wp + ((size_t)(((kc >> 3) + q) * N) + m) * 8;
        #pragma unroll
        for (int t = 0; t < NT; t++) {
            bfrag8 bf_ = *(const bfrag8*)(bbase + t * 128);
            acc[t] = __builtin_amdgcn_mfma_f32_16x16x32_bf16(af, bf_, acc[t], 0, 0, 0);
        }
    }
    #pragma unroll
    for (int r = 0; r < 4; r++) {
        int gr = row0 + q * 4 + r;
        if (gr < M) {
            int dO = deg[gr]; if (dO < 1) dO = 1;
            float s = rsqrtf((float)dO);
            #pragma unroll
            for (int t = 0; t < NT; t++)
                out[(size_t)gr * N + t * 16 + m] = f2bf(acc[t][r] * s);
        }
    }
}

// ===== launch 3: per-bucket counting sort + row_ptr (0..195) | layer-1 gemm (196..977) | perm (978..1233) =====
__global__ __launch_bounds__(256) void sort_gemm(const u32* __restrict__ sbuf, const int* __restrict__ part1,
                                                 u32* __restrict__ sorted, int* __restrict__ rp,
                                                 const float* __restrict__ x, const u16* __restrict__ Wp1,
                                                 const int* __restrict__ deg_out, const int* __restrict__ deg_in,
                                                 const int* __restrict__ gdh, int* __restrict__ perm,
                                                 u16* __restrict__ h, int nE) {
    int b = blockIdx.x, t = threadIdx.x;
    if (b < NBUCK) {
        __shared__ int sd[256];
        __shared__ int cnt[256];
        __shared__ int cursor[256];
        // bucket bounds from digit totals
        int v = part1[t];
        sd[t] = v;
        __syncthreads();
        #pragma unroll
        for (int o = 1; o < 256; o <<= 1) {
            int add = (t >= o) ? sd[t - o] : 0;
            __syncthreads();
            sd[t] += add;
            __syncthreads();
        }
        __shared__ int bs_s, bl_s;
        if (t == b) { bs_s = sd[t] - v; bl_s = v; }
        __syncthreads();
        int bstart = bs_s, bend = bstart + bl_s;
        // sweep 1: count low bytes
        cnt[t] = 0;
        __syncthreads();
        for (int i = bstart + t; i < bend; i += 256)
            atomicAdd(&cnt[(sbuf[i] >> 16) & 255u], 1);
        __syncthreads();
        // scan counts -> row_ptr + cursors
        int cv = cnt[t];
        sd[t] = cv;
        __syncthreads();
        #pragma unroll
        for (int o = 1; o < 256; o <<= 1) {
            int add = (t >= o) ? sd[t - o] : 0;
            __syncthreads();
            sd[t] += add;
            __syncthreads();
        }
        int excl = sd[t] - cv;
        int node = b * 256 + t;
        if (node < NNODES) rp[node] = bstart + excl;
        if (b == NBUCK - 1 && t == 0) rp[NNODES] = nE;
        cursor[t] = excl;
        __syncthreads();
        // sweep 2: place (unstable within node — aggregation is commutative)
        for (int i = bstart + t; i < bend; i += 256) {
            u32 el = sbuf[i];
            int r = atomicAdd(&cursor[(el >> 16) & 255u], 1);
            sorted[bstart + r] = el;
        }
    } else if (b < NBUCK + GB1) {
        gemm_body<256, 128, true>(x, Wp1, deg_out, h, NNODES, b - NBUCK);
    } else {
        // perm scatter; each block derives its own cursors from gdh (replaces the gbase launch-phase)
        int pb = b - NBUCK - GB1;          // 0..255
        __shared__ int cse[64];
        __shared__ int cur[64];
        if (t < 64) {
            int s_all = 0, s_pre = 0;
            for (int q2 = 0; q2 < PBN; q2++) {
                int v = gdh[q2 * 64 + t];
                s_all += v;
                s_pre += (q2 < pb) ? v : 0;
            }
            cse[t] = s_all;
            cur[t] = s_pre;
        }
        __syncthreads();
        if (t == 0) {
            int s = 0;
            for (int d2 = 0; d2 < 64; d2++) { int v = cse[d2]; cse[d2] = s; s += v; }
        }
        __syncthreads();
        if (t < 64) cur[t] += cse[t];
        __syncthreads();
        int n = pb * PBR + t;
        if (t < PBR && n < NNODES) {
            int d = deg_in[n]; d = d > 63 ? 63 : d;
            int p = atomicAdd(&cur[d], 1);
            perm[p] = n;
        }
    }
}

// ---- launch 4: layer-1 gather FUSED with layer-2 gemm (bit-identical to former pair; see round-4 note) ----
__global__ __launch_bounds__(256) void gather1f(const uint4* __restrict__ h, const int* __restrict__ row_ptr,
                                                const u32* __restrict__ sorted, const float* __restrict__ b1,
                                                const int* __restrict__ perm, const int* __restrict__ deg_out,
                                                const u16* __restrict__ Wp2, u16* __restrict__ h2) {
    __shared__ __align__(16) u16 sh[16 * 136];   // 16 rows x (128 + 8 pad) bf16
    int t = threadIdx.x;
    int qw = t >> 4;                       // block-local node index 0..15
    int l = t & 15;
    int g = blockIdx.x * 16 + qw;          // 3125 blocks x 16 = 50000 exact
    int node = perm[g];
    int beg = row_ptr[node], end = row_ptr[node + 1];
    float a[8] = {0.f, 0.f, 0.f, 0.f, 0.f, 0.f, 0.f, 0.f};
    for (int e = beg; e < end; e += 8) {
        uint4 p[8];
        #pragma unroll
        for (int j = 0; j < 8; j++) {
            int ee = e + j; ee = (ee < end - 1) ? ee : end - 1;
            p[j] = h[(size_t)(sorted[ee] & 0xFFFFu) * 16 + l];
        }
        #pragma unroll
        for (int j = 0; j < 8; j++)
            if (e + j < end) {
                a[0] += bflo(p[j].x); a[1] += bfhi(p[j].x);
                a[2] += bflo(p[j].y); a[3] += bfhi(p[j].y);
                a[4] += bflo(p[j].z); a[5] += bfhi(p[j].z);
                a[6] += bflo(p[j].w); a[7] += bfhi(p[j].w);
            }
    }
    int dI = end - beg; if (dI < 1) dI = 1;
    float r = rsqrtf((float)dI);
    const float4 bA = *(const float4*)(b1 + 8 * l);
    const float4 bB = *(const float4*)(b1 + 8 * l + 4);
    float v0 = fmaxf(a[0] * r + bA.x, 0.f), v1 = fmaxf(a[1] * r + bA.y, 0.f);
    float v2 = fmaxf(a[2] * r + bA.z, 0.f), v3 = fmaxf(a[3] * r + bA.w, 0.f);
    float v4 = fmaxf(a[4] * r + bB.x, 0.f), v5 = fmaxf(a[5] * r + bB.y, 0.f);
    float v6 = fmaxf(a[6] * r + bB.z, 0.f), v7 = fmaxf(a[7] * r + bB.w, 0.f);
    uint4 o;
    o.x = ((u32)f2bf(v1) << 16) | f2bf(v0);
    o.y = ((u32)f2bf(v3) << 16) | f2bf(v2);
    o.z = ((u32)f2bf(v5) << 16) | f2bf(v4);
    o.w = ((u32)f2bf(v7) << 16) | f2bf(v6);
    *(uint4*)&sh[qw * 136 + l * 8] = o;    // features [8l..8l+8) of row qw
    __syncthreads();
    // ---- layer-2 gemm tile: wave w computes cols [16w, 16w+16) of all 16 rows ----
    const int lane = t & 63;
    const int m = lane & 15;
    const int q = lane >> 4;
    const int w = t >> 6;
    f32x4 acc = (f32x4){0.f, 0.f, 0.f, 0.f};
    #pragma unroll
    for (int kc = 0; kc < 128; kc += 32) {
        bfrag8 af = *(const bfrag8*)&sh[m * 136 + q * 8 + kc];
        bfrag8 bf_ = *(const bfrag8*)(Wp2 + ((size_t)(((kc >> 3) + q) * 64) + w * 16 + m) * 8);
        acc = __builtin_amdgcn_mfma_f32_16x16x32_bf16(af, bf_, acc, 0, 0, 0);
    }
    #pragma unroll
    for (int rr = 0; rr < 4; rr++) {
        int li = q * 4 + rr;               // block-local row
        int nd = perm[blockIdx.x * 16 + li];
        int dO = deg_out[nd]; if (dO < 1) dO = 1;
        float s = rsqrtf((float)dO);
        h2[(size_t)nd * 64 + w * 16 + m] = f2bf(acc[rr] * s);
    }
}

// ---- launch 5: layer-2 gather + projection: eighth-wave per node, degree-balanced via perm ----
__global__ __launch_bounds__(256) void gather2(const uint4* __restrict__ h2, const int* __restrict__ row_ptr,
                                               const u32* __restrict__ sorted, const float* __restrict__ b2,
                                               const float* __restrict__ Wf, const float* __restrict__ bfv,
                                               const int* __restrict__ perm,
                                               float* __restrict__ logits, float* __restrict__ hidden, int nNodes) {
    int g = (blockIdx.x * 256 + threadIdx.x) >> 3;
    int l = threadIdx.x & 7;
    if (g >= nNodes) return;
    int node = perm[g];
    int beg = row_ptr[node], end = row_ptr[node + 1];
    float a[8] = {0.f, 0.f, 0.f, 0.f, 0.f, 0.f, 0.f, 0.f};
    for (int e = beg; e < end; e += 8) {
        uint4 p[8];
        #pragma unroll
        for (int j = 0; j < 8; j++) {
            int ee = e + j; ee = (ee < end - 1) ? ee : end - 1;
            p[j] = h2[(size_t)(sorted[ee] & 0xFFFFu) * 8 + l];
        }
        #pragma unroll
        for (int j = 0; j < 8; j++)
            if (e + j < end) {
                a[0] += bflo(p[j].x); a[1] += bfhi(p[j].x);
                a[2] += bflo(p[j].y); a[3] += bfhi(p[j].y);
                a[4] += bflo(p[j].z); a[5] += bfhi(p[j].z);
                a[6] += bflo(p[j].w); a[7] += bfhi(p[j].w);
            }
    }
    int dI = end - beg; if (dI < 1) dI = 1;
    float r = rsqrtf((float)dI);
    float v[8];
    #pragma unroll
    for (int f = 0; f < 8; f++) v[f] = a[f] * r + b2[8 * l + f];
    float4 oA = {v[0], v[1], v[2], v[3]};
    float4 oB = {v[4], v[5], v[6], v[7]};
    ((float4*)hidden)[(size_t)node * 16 + 2 * l + 0] = oA;
    ((float4*)hidden)[(size_t)node * 16 + 2 * l + 1] = oB;
    float l0 = 0.f, l1 = 0.f;
    #pragma unroll
    for (int f = 0; f < 8; f++) {
        l0 += v[f] * Wf[(8 * l + f) * 2 + 0];
        l1 += v[f] * Wf[(8 * l + f) * 2 + 1];
    }
    #pragma unroll
    for (int off = 4; off > 0; off >>= 1) {
        l0 += __shfl_down(l0, off, 8);
        l1 += __shfl_down(l1, off, 8);
    }
    if (l == 0) {
        logits[(size_t)node * 2 + 0] = l0 + bfv[0];
        logits[(size_t)node * 2 + 1] = l1 + bfv[1];
    }
}

extern "C" void kernel_launch(void* const* d_in, const int* in_sizes, int n_in,
                              void* d_out, int out_size, void* d_ws, size_t ws_size,
                              hipStream_t stream) {
    const float* x   = (const float*)d_in[0];
    const float* W1  = (const float*)d_in[1];
    const float* b1  = (const float*)d_in[2];
    const float* W2  = (const float*)d_in[3];
    const float* b2  = (const float*)d_in[4];
    const float* Wf  = (const float*)d_in[5];
    const float* bfv = (const float*)d_in[6];
    const int* src = (const int*)d_in[7];
    const int* dst = (const int*)d_in[8];

    float* out_logits = (float*)d_out;
    float* out_hidden = (float*)d_out + 2 * NNODES;

    char* ws = (char*)d_ws;
    size_t off = 0;
    auto alloc = [&](size_t bytes) { void* p = ws + off; off += (bytes + 255) & ~(size_t)255; return p; };
    u16*   gh1     = (u16*)alloc(NCH * NCH * 2);            // 128 KB, [chunk][digit]
    int*   part1   = (int*)alloc(256 * 4);
    u32*   sbuf    = (u32*)alloc((size_t)NEDGES * 4);
    u32*   sorted  = (u32*)alloc((size_t)NEDGES * 4);
    u32*   histS   = (u32*)alloc((size_t)SHB * 12500 * 4);  // 3.2 MB u8-packed partials
    u32*   histD   = (u32*)alloc((size_t)SHB * 12500 * 4);  // 3.2 MB
    int*   deg     = (int*)alloc(2 * NNODES * 4);           // [0..N)=deg_out, [N..2N)=deg_in
    int*   row_ptr = (int*)alloc((NNODES + 1) * 4);
    int*   gdh     = (int*)alloc(PBN * 64 * 4);
    int*   perm    = (int*)alloc(NNODES * 4);
    u16*   Wp1     = (u16*)alloc(256 * 128 * 2);
    u16*   Wp2     = (u16*)alloc(128 * 64 * 2);
    u16*   h       = (u16*)alloc((size_t)NNODES * 128 * 2);
    u16*   h2      = (u16*)alloc((size_t)NNODES * 64 * 2);

    int* deg_out = deg;
    int* deg_in  = deg + NNODES;

    // 1: u8 degree hists + partition hist (dst>>8) + weight prep (all uint4 edge loads)
    pre_kernel<<<2 * SHB + NCH + 128, 256, 0, stream>>>(W1, W2, Wp1, Wp2, src, dst, histS, histD, gh1, NEDGES);
    // 2: partition scatter + deg reduce + gdh (merged old red_scan1 + scatter1)
    scat_deg<<<NCH, 256, 0, stream>>>(src, dst, gh1, histS, histD, deg_out, deg_in, gdh, part1, sbuf, NEDGES);
    // 3: per-bucket counting sort + row_ptr || layer-1 gemm || perm scatter (independent, fused launch)
    sort_gemm<<<NBUCK + GB1 + PBN, 256, 0, stream>>>(sbuf, part1, sorted, row_ptr, x, Wp1,
                                                     deg_out, deg_in, gdh, perm, h, NEDGES);
    // 4: layer-1 gather fused with layer-2 gemm (degree-balanced; h1 round-trip eliminated)
    gather1f<<<NNODES / 16, 256, 0, stream>>>((const uint4*)h, row_ptr, sorted, b1, perm, deg_out, Wp2, h2);
    // 5: layer-2 gather + projection (degree-balanced)
    gather2<<<(NNODES * 8 + 255) / 256, 256, 0, stream>>>((const uint4*)h2, row_ptr, sorted, b2, Wf, bfv,
                                                          perm, out_logits, out_hidden, NNODES);
}